// Round 1
// baseline (8268.003 us; speedup 1.0000x reference)
//
#include <hip/hip_runtime.h>
#include <hip/hip_bf16.h>
#include <math.h>

// Problem constants
#define BATCH   2
#define SEQ     2048
#define NKNOW   2048
#define DMODEL  1024
#define NHEADS  16
#define HDIM    64
#define TOPK    32
// SCALE = 8.0 -> multiply scores by 0.125f

// ---------------------------------------------------------------------------
// GEMM: Y[M,1024] = X[M,1024] @ W[1024,1024]^T + bias   (fp32)
// M = 4096 fixed. 128x128 tile, BK=16, 256 threads, 8x8 micro.
// ---------------------------------------------------------------------------
__global__ __launch_bounds__(256) void gemm_xwt_bias(
    const float* __restrict__ X, const float* __restrict__ W,
    const float* __restrict__ bias, float* __restrict__ Y)
{
    __shared__ float As[16][132];
    __shared__ float Bs[16][132];

    const int t  = threadIdx.x;
    const int m0 = blockIdx.x * 128;
    const int n0 = blockIdx.y * 128;

    const int lm = t >> 2;          // 0..63 staging row
    const int lk = (t & 3) << 2;    // 0,4,8,12 staging k offset

    const int tx = t & 15;          // col group: cols tx*4..+3 and 64+tx*4..+3
    const int ty = t >> 4;          // row group: rows ty*8..+7

    float acc[8][8];
#pragma unroll
    for (int i = 0; i < 8; ++i)
#pragma unroll
        for (int j = 0; j < 8; ++j) acc[i][j] = 0.f;

    for (int k0 = 0; k0 < 1024; k0 += 16) {
        float4 a0 = *(const float4*)(X + (size_t)(m0 + lm) * 1024 + k0 + lk);
        float4 a1 = *(const float4*)(X + (size_t)(m0 + lm + 64) * 1024 + k0 + lk);
        float4 b0 = *(const float4*)(W + (size_t)(n0 + lm) * 1024 + k0 + lk);
        float4 b1 = *(const float4*)(W + (size_t)(n0 + lm + 64) * 1024 + k0 + lk);
        __syncthreads();
        As[lk + 0][lm] = a0.x; As[lk + 1][lm] = a0.y; As[lk + 2][lm] = a0.z; As[lk + 3][lm] = a0.w;
        As[lk + 0][lm + 64] = a1.x; As[lk + 1][lm + 64] = a1.y; As[lk + 2][lm + 64] = a1.z; As[lk + 3][lm + 64] = a1.w;
        Bs[lk + 0][lm] = b0.x; Bs[lk + 1][lm] = b0.y; Bs[lk + 2][lm] = b0.z; Bs[lk + 3][lm] = b0.w;
        Bs[lk + 0][lm + 64] = b1.x; Bs[lk + 1][lm + 64] = b1.y; Bs[lk + 2][lm + 64] = b1.z; Bs[lk + 3][lm + 64] = b1.w;
        __syncthreads();
#pragma unroll
        for (int k = 0; k < 16; ++k) {
            float a[8], b[8];
            *(float4*)(a)     = *(const float4*)&As[k][ty * 8];
            *(float4*)(a + 4) = *(const float4*)&As[k][ty * 8 + 4];
            *(float4*)(b)     = *(const float4*)&Bs[k][tx * 4];        // cols tx*4..+3
            *(float4*)(b + 4) = *(const float4*)&Bs[k][64 + tx * 4];   // cols 64+tx*4..+3
#pragma unroll
            for (int i = 0; i < 8; ++i)
#pragma unroll
                for (int j = 0; j < 8; ++j)
                    acc[i][j] = fmaf(a[i], b[j], acc[i][j]);
        }
    }

    float4 bv0 = *(const float4*)(bias + n0 + tx * 4);
    float4 bv1 = *(const float4*)(bias + n0 + 64 + tx * 4);
#pragma unroll
    for (int i = 0; i < 8; ++i) {
        size_t row = (size_t)(m0 + ty * 8 + i) * 1024;
        float4 r0, r1;
        r0.x = acc[i][0] + bv0.x; r0.y = acc[i][1] + bv0.y;
        r0.z = acc[i][2] + bv0.z; r0.w = acc[i][3] + bv0.w;
        r1.x = acc[i][4] + bv1.x; r1.y = acc[i][5] + bv1.y;
        r1.z = acc[i][6] + bv1.z; r1.w = acc[i][7] + bv1.w;
        *(float4*)(Y + row + n0 + tx * 4)      = r0;
        *(float4*)(Y + row + n0 + 64 + tx * 4) = r1;
    }
}

// ---------------------------------------------------------------------------
// Fused attention: per block = (b, h, 64 query rows).
// Streams K in 64-col chunks; scores -> LDS; wave0 streaming top-32 per row
// (strict >, so ties keep the earlier index, matching jax.lax.top_k);
// threads 64..255 prefetch next K chunk; epilogue softmax + V gather.
// ---------------------------------------------------------------------------
__global__ __launch_bounds__(256) void attn_topk(
    const float* __restrict__ Qp, const float* __restrict__ Kp,
    const float* __restrict__ Vp, float* __restrict__ ctx)
{
    __shared__ float Qs[64][68];
    __shared__ float Ks[64][68];
    __shared__ float Ss[64][65];
    __shared__ float topv[64][33];
    __shared__ unsigned short topi[64][33];

    const int t     = threadIdx.x;
    const int stile = blockIdx.x & 31;
    const int h     = (blockIdx.x >> 5) & 15;
    const int b     = blockIdx.x >> 9;
    const int s0    = stile * 64;

    const size_t qbase = ((size_t)b * SEQ + s0) * DMODEL + h * HDIM;
    const size_t kbase = ((size_t)b * NKNOW) * DMODEL + h * HDIM;

    // stage Q tile (64 rows x 64 floats)
    {
        const int r = t >> 2, q = t & 3;
#pragma unroll
        for (int it = 0; it < 4; ++it) {
            float4 v = *(const float4*)(Qp + qbase + (size_t)r * DMODEL + (q + it * 4) * 4);
            *(float4*)&Qs[r][(q + it * 4) * 4] = v;
        }
    }
    // init top-k lists
    for (int i = t; i < 64 * 33; i += 256) ((float*)topv)[i] = -3.0e38f;
    // stage K chunk 0
    {
        const int r = t >> 2, q = t & 3;
#pragma unroll
        for (int it = 0; it < 4; ++it) {
            float4 v = *(const float4*)(Kp + kbase + (size_t)r * DMODEL + (q + it * 4) * 4);
            *(float4*)&Ks[r][(q + it * 4) * 4] = v;
        }
    }

    float thr = -3.0e38f;            // running min of this lane's top-32 (t<64)
    const int rr = t >> 4;           // phase A rows: rr + 16*i
    const int cc = t & 15;           // phase A cols: cc + 16*j

    for (int ci = 0; ci < 32; ++ci) {
        __syncthreads();   // staging of chunk ci done; previous phase B done with Ss

        // ---- phase A: 64x64 score tile, 4x4 micro per thread ----
        float acc[4][4];
#pragma unroll
        for (int i = 0; i < 4; ++i)
#pragma unroll
            for (int j = 0; j < 4; ++j) acc[i][j] = 0.f;

#pragma unroll
        for (int dd = 0; dd < 64; dd += 4) {
            float4 qf[4], kf[4];
#pragma unroll
            for (int i = 0; i < 4; ++i) qf[i] = *(const float4*)&Qs[rr + 16 * i][dd];
#pragma unroll
            for (int j = 0; j < 4; ++j) kf[j] = *(const float4*)&Ks[cc + 16 * j][dd];
#pragma unroll
            for (int i = 0; i < 4; ++i)
#pragma unroll
                for (int j = 0; j < 4; ++j) {
                    acc[i][j] = fmaf(qf[i].x, kf[j].x, acc[i][j]);
                    acc[i][j] = fmaf(qf[i].y, kf[j].y, acc[i][j]);
                    acc[i][j] = fmaf(qf[i].z, kf[j].z, acc[i][j]);
                    acc[i][j] = fmaf(qf[i].w, kf[j].w, acc[i][j]);
                }
        }
#pragma unroll
        for (int i = 0; i < 4; ++i)
#pragma unroll
            for (int j = 0; j < 4; ++j)
                Ss[rr + 16 * i][cc + 16 * j] = acc[i][j] * 0.125f;

        __syncthreads();

        // ---- phase B (wave0): streaming top-32 ---- / ---- others: prefetch ----
        if (t < 64) {
            const int r = t;
            for (int c = 0; c < 64; ++c) {
                float s = Ss[r][c];
                if (s > thr) {
                    float mn = topv[r][0]; int pos = 0; float mn2 = 3.0e38f;
#pragma unroll 4
                    for (int j = 1; j < 32; ++j) {
                        float v = topv[r][j];
                        if (v < mn) { mn2 = mn; mn = v; pos = j; }
                        else if (v < mn2) { mn2 = v; }
                    }
                    topv[r][pos] = s;
                    topi[r][pos] = (unsigned short)(ci * 64 + c);
                    thr = fminf(mn2, s);
                }
            }
        } else if (ci + 1 < 32) {
            const int tt = t - 64;
            for (int i = tt; i < 1024; i += 192) {
                const int r = i >> 4, q = i & 15;
                float4 v = *(const float4*)(Kp + kbase + (size_t)((ci + 1) * 64 + r) * DMODEL + q * 4);
                *(float4*)&Ks[r][q * 4] = v;
            }
        }
    }
    __syncthreads();

    // ---- phase C: softmax over top-32 + gathered V contraction ----
    {
        const int r = t >> 2, part = t & 3, d0 = part * 16;
        float m = -3.0e38f;
#pragma unroll
        for (int j = 0; j < 32; ++j) m = fmaxf(m, topv[r][j]);
        float Z = 0.f;
#pragma unroll
        for (int j = 0; j < 32; ++j) Z += __expf(topv[r][j] - m);
        const float inv = 1.0f / Z;

        float4 a0 = {0, 0, 0, 0}, a1 = {0, 0, 0, 0}, a2 = {0, 0, 0, 0}, a3 = {0, 0, 0, 0};
#pragma unroll
        for (int j = 0; j < 32; ++j) {
            const float w = __expf(topv[r][j] - m) * inv;
            const int idx = topi[r][j];
            const float* vp = Vp + ((size_t)b * NKNOW + idx) * DMODEL + h * HDIM + d0;
            float4 v0 = *(const float4*)(vp);
            float4 v1 = *(const float4*)(vp + 4);
            float4 v2 = *(const float4*)(vp + 8);
            float4 v3 = *(const float4*)(vp + 12);
            a0.x = fmaf(w, v0.x, a0.x); a0.y = fmaf(w, v0.y, a0.y);
            a0.z = fmaf(w, v0.z, a0.z); a0.w = fmaf(w, v0.w, a0.w);
            a1.x = fmaf(w, v1.x, a1.x); a1.y = fmaf(w, v1.y, a1.y);
            a1.z = fmaf(w, v1.z, a1.z); a1.w = fmaf(w, v1.w, a1.w);
            a2.x = fmaf(w, v2.x, a2.x); a2.y = fmaf(w, v2.y, a2.y);
            a2.z = fmaf(w, v2.z, a2.z); a2.w = fmaf(w, v2.w, a2.w);
            a3.x = fmaf(w, v3.x, a3.x); a3.y = fmaf(w, v3.y, a3.y);
            a3.z = fmaf(w, v3.z, a3.z); a3.w = fmaf(w, v3.w, a3.w);
        }
        float* op = ctx + ((size_t)b * SEQ + s0 + r) * DMODEL + h * HDIM + d0;
        *(float4*)(op)      = a0;
        *(float4*)(op + 4)  = a1;
        *(float4*)(op + 8)  = a2;
        *(float4*)(op + 12) = a3;
    }
}

// ---------------------------------------------------------------------------
extern "C" void kernel_launch(void* const* d_in, const int* in_sizes, int n_in,
                              void* d_out, int out_size, void* d_ws, size_t ws_size,
                              hipStream_t stream)
{
    const float* x  = (const float*)d_in[0];
    const float* ke = (const float*)d_in[1];
    const float* Wq = (const float*)d_in[2];
    const float* bq = (const float*)d_in[3];
    const float* Wk = (const float*)d_in[4];
    const float* bk = (const float*)d_in[5];
    const float* Wv = (const float*)d_in[6];
    const float* bv = (const float*)d_in[7];
    const float* Wo = (const float*)d_in[8];
    const float* bo = (const float*)d_in[9];
    float* out = (float*)d_out;

    // workspace layout (floats)
    float* Qp  = (float*)d_ws;                 // 4096x1024
    float* Kp  = Qp + (size_t)4096 * 1024;     // 4096x1024
    float* Vp  = Kp + (size_t)4096 * 1024;     // 4096x1024
    float* ctx = Vp + (size_t)4096 * 1024;     // 4096x1024

    dim3 ggrid(32, 8);
    dim3 gblk(256);

    hipLaunchKernelGGL(gemm_xwt_bias, ggrid, gblk, 0, stream, x,  Wq, bq, Qp);
    hipLaunchKernelGGL(gemm_xwt_bias, ggrid, gblk, 0, stream, ke, Wk, bk, Kp);
    hipLaunchKernelGGL(gemm_xwt_bias, ggrid, gblk, 0, stream, ke, Wv, bv, Vp);

    hipLaunchKernelGGL(attn_topk, dim3(BATCH * NHEADS * (SEQ / 64)), gblk, 0, stream,
                       Qp, Kp, Vp, ctx);

    hipLaunchKernelGGL(gemm_xwt_bias, ggrid, gblk, 0, stream, ctx, Wo, bo, out);
}

// Round 2
// 2137.975 us; speedup vs baseline: 3.8672x; 3.8672x over previous
//
#include <hip/hip_runtime.h>
#include <hip/hip_bf16.h>
#include <math.h>

typedef unsigned long long u64;
typedef unsigned int u32;

#define BATCH   2
#define SEQ     2048
#define NKNOW   2048
#define DMODEL  1024
#define NHEADS  16
#define HDIM    64
#define TOPK    32
// SCALE = sqrt(64) = 8 -> multiply scores by 0.125f

// ---------------------------------------------------------------------------
// GEMM: Y[4096,1024] = X[4096,1024] @ W[1024,1024]^T + bias   (fp32)
// 128x128 tile, BK=16, 256 threads, 8x8 micro. (unchanged from R0)
// ---------------------------------------------------------------------------
__global__ __launch_bounds__(256) void gemm_xwt_bias(
    const float* __restrict__ X, const float* __restrict__ W,
    const float* __restrict__ bias, float* __restrict__ Y)
{
    __shared__ float As[16][132];
    __shared__ float Bs[16][132];

    const int t  = threadIdx.x;
    const int m0 = blockIdx.x * 128;
    const int n0 = blockIdx.y * 128;

    const int lm = t >> 2;
    const int lk = (t & 3) << 2;

    const int tx = t & 15;
    const int ty = t >> 4;

    float acc[8][8];
#pragma unroll
    for (int i = 0; i < 8; ++i)
#pragma unroll
        for (int j = 0; j < 8; ++j) acc[i][j] = 0.f;

    for (int k0 = 0; k0 < 1024; k0 += 16) {
        float4 a0 = *(const float4*)(X + (size_t)(m0 + lm) * 1024 + k0 + lk);
        float4 a1 = *(const float4*)(X + (size_t)(m0 + lm + 64) * 1024 + k0 + lk);
        float4 b0 = *(const float4*)(W + (size_t)(n0 + lm) * 1024 + k0 + lk);
        float4 b1 = *(const float4*)(W + (size_t)(n0 + lm + 64) * 1024 + k0 + lk);
        __syncthreads();
        As[lk + 0][lm] = a0.x; As[lk + 1][lm] = a0.y; As[lk + 2][lm] = a0.z; As[lk + 3][lm] = a0.w;
        As[lk + 0][lm + 64] = a1.x; As[lk + 1][lm + 64] = a1.y; As[lk + 2][lm + 64] = a1.z; As[lk + 3][lm + 64] = a1.w;
        Bs[lk + 0][lm] = b0.x; Bs[lk + 1][lm] = b0.y; Bs[lk + 2][lm] = b0.z; Bs[lk + 3][lm] = b0.w;
        Bs[lk + 0][lm + 64] = b1.x; Bs[lk + 1][lm + 64] = b1.y; Bs[lk + 2][lm + 64] = b1.z; Bs[lk + 3][lm + 64] = b1.w;
        __syncthreads();
#pragma unroll
        for (int k = 0; k < 16; ++k) {
            float a[8], b[8];
            *(float4*)(a)     = *(const float4*)&As[k][ty * 8];
            *(float4*)(a + 4) = *(const float4*)&As[k][ty * 8 + 4];
            *(float4*)(b)     = *(const float4*)&Bs[k][tx * 4];
            *(float4*)(b + 4) = *(const float4*)&Bs[k][64 + tx * 4];
#pragma unroll
            for (int i = 0; i < 8; ++i)
#pragma unroll
                for (int j = 0; j < 8; ++j)
                    acc[i][j] = fmaf(a[i], b[j], acc[i][j]);
        }
    }

    float4 bv0 = *(const float4*)(bias + n0 + tx * 4);
    float4 bv1 = *(const float4*)(bias + n0 + 64 + tx * 4);
#pragma unroll
    for (int i = 0; i < 8; ++i) {
        size_t row = (size_t)(m0 + ty * 8 + i) * 1024;
        float4 r0, r1;
        r0.x = acc[i][0] + bv0.x; r0.y = acc[i][1] + bv0.y;
        r0.z = acc[i][2] + bv0.z; r0.w = acc[i][3] + bv0.w;
        r1.x = acc[i][4] + bv1.x; r1.y = acc[i][5] + bv1.y;
        r1.z = acc[i][6] + bv1.z; r1.w = acc[i][7] + bv1.w;
        *(float4*)(Y + row + n0 + tx * 4)      = r0;
        *(float4*)(Y + row + n0 + 64 + tx * 4) = r1;
    }
}

// ---------------------------------------------------------------------------
// Scores chunk GEMM: Sc[bhl, s, nn] = Q[s,:] . K[p*NC+nn,:] * 0.125
// per (b,h). 128x128 tile, K=64 (single stage). Tiles stored transposed in
// LDS ([64][128] unpadded = exactly 64KB total; reads are conflict-free,
// staging stores take a 4-way conflict - staging is ~5% of block time).
// ---------------------------------------------------------------------------
__global__ __launch_bounds__(256) void scores_gemm(
    const float* __restrict__ Qp, const float* __restrict__ Kp,
    float* __restrict__ Sc, int p, int NC, int bh0)
{
    __shared__ float As[64][128];
    __shared__ float Bs[64][128];

    const int t   = threadIdx.x;
    const int s0  = blockIdx.x * 128;
    const int nn0 = blockIdx.y * 128;
    const int bhl = blockIdx.z;        // local bh within this chunk
    const int bh  = bh0 + bhl;
    const int b   = bh >> 4, h = bh & 15;

    // stage transposed: As[d][r] = Q[s0+r][h*64+d]; Bs[d][r] = K[p*NC+nn0+r][h*64+d]
    {
        const int g  = t & 3;
        const int r0 = t >> 2;
#pragma unroll
        for (int it = 0; it < 2; ++it) {
            const int r = r0 + 64 * it;
            const float* srcQ = Qp + ((size_t)b * SEQ + s0 + r) * DMODEL + h * HDIM + g * 16;
            const float* srcK = Kp + ((size_t)b * NKNOW + (size_t)p * NC + nn0 + r) * DMODEL + h * HDIM + g * 16;
#pragma unroll
            for (int u = 0; u < 4; ++u) {
                float4 v = *(const float4*)(srcQ + u * 4);
                const int d = g * 16 + u * 4;
                As[d + 0][r] = v.x; As[d + 1][r] = v.y; As[d + 2][r] = v.z; As[d + 3][r] = v.w;
            }
#pragma unroll
            for (int u = 0; u < 4; ++u) {
                float4 v = *(const float4*)(srcK + u * 4);
                const int d = g * 16 + u * 4;
                Bs[d + 0][r] = v.x; Bs[d + 1][r] = v.y; Bs[d + 2][r] = v.z; Bs[d + 3][r] = v.w;
            }
        }
    }
    __syncthreads();

    const int tx = t & 15, ty = t >> 4;
    float acc[8][8];
#pragma unroll
    for (int i = 0; i < 8; ++i)
#pragma unroll
        for (int j = 0; j < 8; ++j) acc[i][j] = 0.f;

#pragma unroll 4
    for (int k = 0; k < 64; ++k) {
        float a[8], bb[8];
        *(float4*)(a)      = *(const float4*)&As[k][ty * 8];
        *(float4*)(a + 4)  = *(const float4*)&As[k][ty * 8 + 4];
        *(float4*)(bb)     = *(const float4*)&Bs[k][tx * 4];
        *(float4*)(bb + 4) = *(const float4*)&Bs[k][64 + tx * 4];
#pragma unroll
        for (int i = 0; i < 8; ++i)
#pragma unroll
            for (int j = 0; j < 8; ++j)
                acc[i][j] = fmaf(a[i], bb[j], acc[i][j]);
    }

#pragma unroll
    for (int i = 0; i < 8; ++i) {
        float* dst = Sc + ((size_t)bhl * SEQ + s0 + ty * 8 + i) * NC + nn0;
        float4 r0, r1;
        r0.x = acc[i][0] * 0.125f; r0.y = acc[i][1] * 0.125f;
        r0.z = acc[i][2] * 0.125f; r0.w = acc[i][3] * 0.125f;
        r1.x = acc[i][4] * 0.125f; r1.y = acc[i][5] * 0.125f;
        r1.z = acc[i][6] * 0.125f; r1.w = acc[i][7] * 0.125f;
        *(float4*)(dst + tx * 4)      = r0;
        *(float4*)(dst + 64 + tx * 4) = r1;
    }
}

// ---------------------------------------------------------------------------
// Top-k pass: one WAVE per (b,h,s) row. Each lane packs its NC/64 chunk
// scores as u64 keys (monotone fp32 map in hi32, ~col in lo32 -> exact
// jax.lax.top_k tie semantics), sorts them (Batcher-8, branch-free), then
// 32 wave-wide u64-max butterflies pop the exact top-32 of chunk U carry.
// Non-final passes write the carry; final pass does softmax + V gather.
// ---------------------------------------------------------------------------
__device__ __forceinline__ u32 mkey_of(float v) {
    u32 u = __float_as_uint(v);
    return (u & 0x80000000u) ? ~u : (u | 0x80000000u);
}
__device__ __forceinline__ float val_of(u32 mk) {
    u32 u = (mk & 0x80000000u) ? (mk ^ 0x80000000u) : ~mk;
    return __uint_as_float(u);
}
__device__ __forceinline__ u64 packkey(float v, int col) {
    return (((u64)mkey_of(v)) << 32) | (u32)(~(u32)col);
}

#define CE(i, j) { u64 _a = kreg[i], _b = kreg[j]; \
                   u64 _mx = _a > _b ? _a : _b; u64 _mn = _a > _b ? _b : _a; \
                   kreg[i] = _mx; kreg[j] = _mn; }

__global__ __launch_bounds__(256) void topk_pass(
    const float* __restrict__ Sc, u64* __restrict__ carry,
    const float* __restrict__ Vp, float* __restrict__ ctx,
    int p, int NC, int use_carry, int is_final, int bh0)
{
    __shared__ u64 stripe[4][64][9];
    __shared__ u64 rowlist[4][32];

    const int t = threadIdx.x;
    const int w = t >> 6;
    const int l = t & 63;

    const int Rl  = blockIdx.x * 4 + w;     // local row within bh-chunk
    const int bhl = Rl >> 11;
    const int s   = Rl & 2047;
    const int bh  = bh0 + bhl;
    const int b   = bh >> 4, h = bh & 15;
    const size_t Rg = (size_t)bh * SEQ + s; // global row for carry indexing

    // ---- load + pack this lane's chunk scores ----
    u64 kreg[8];
#pragma unroll
    for (int q = 0; q < 8; ++q) kreg[q] = 0;

    const float* srow = Sc + ((size_t)bhl * SEQ + s) * NC;
    if (NC == 512) {
#pragma unroll
        for (int q2 = 0; q2 < 2; ++q2) {
            float4 v = *(const float4*)(srow + q2 * 256 + l * 4);
            int c0 = p * NC + q2 * 256 + l * 4;
            kreg[q2 * 4 + 0] = packkey(v.x, c0 + 0);
            kreg[q2 * 4 + 1] = packkey(v.y, c0 + 1);
            kreg[q2 * 4 + 2] = packkey(v.z, c0 + 2);
            kreg[q2 * 4 + 3] = packkey(v.w, c0 + 3);
        }
    } else { // NC == 256
        float4 v = *(const float4*)(srow + l * 4);
        int c0 = p * NC + l * 4;
        kreg[0] = packkey(v.x, c0 + 0);
        kreg[1] = packkey(v.y, c0 + 1);
        kreg[2] = packkey(v.z, c0 + 2);
        kreg[3] = packkey(v.w, c0 + 3);
    }

    // ---- sort 8 descending (Batcher odd-even mergesort, 19 CE) ----
    CE(0,1) CE(2,3) CE(4,5) CE(6,7)
    CE(0,2) CE(1,3) CE(4,6) CE(5,7)
    CE(1,2) CE(5,6)
    CE(0,4) CE(1,5) CE(2,6) CE(3,7)
    CE(2,4) CE(3,5)
    CE(1,2) CE(3,4) CE(5,6)

    // ---- write sorted stripe (slot 8 = sentinel) ----
    u64* mystripe = &stripe[w][l][0];
#pragma unroll
    for (int q = 0; q < 8; ++q) mystripe[q] = kreg[q];
    mystripe[8] = 0;

    u64 ha  = kreg[0];
    int ptr = 1;
    u64 hc  = (use_carry && l < 32) ? carry[Rg * TOPK + l] : 0;

    // ---- 32 extraction iterations ----
    for (int i = 0; i < 32; ++i) {
        bool fromc = hc > ha;
        u64 cand = fromc ? hc : ha;
        u64 g = cand;
#pragma unroll
        for (int d = 1; d < 64; d <<= 1) {
            u64 o = __shfl_xor(g, d, 64);
            g = o > g ? o : g;
        }
        bool win = (cand == g) && (cand != 0ull);
        if (win) {
            rowlist[w][i] = g;
            if (fromc) {
                hc = 0;
            } else {
                ha = mystripe[ptr];
                ptr++;
            }
        }
    }

    if (is_final) {
        // ---- softmax over the 32 + V gather; lane = output dim ----
        float wv[32];
        u32 cols[32];
        float m = 0.f, Z = 0.f;
#pragma unroll
        for (int j = 0; j < 32; ++j) {
            u64 kk = rowlist[w][j];
            float v = val_of((u32)(kk >> 32));
            cols[j] = ~((u32)kk);
            if (j == 0) m = v;
            float e = __expf(v - m);
            wv[j] = e;
            Z += e;
        }
        const float inv = 1.0f / Z;
        float acc = 0.f;
#pragma unroll
        for (int j = 0; j < 32; ++j) {
            const float* vp = Vp + ((size_t)b * NKNOW + cols[j]) * DMODEL + h * HDIM + l;
            acc = fmaf(wv[j] * inv, *vp, acc);
        }
        ctx[((size_t)b * SEQ + s) * DMODEL + h * HDIM + l] = acc;
    } else {
        if (l < 32) carry[Rg * TOPK + l] = rowlist[w][l];
    }
}

// ---------------------------------------------------------------------------
extern "C" void kernel_launch(void* const* d_in, const int* in_sizes, int n_in,
                              void* d_out, int out_size, void* d_ws, size_t ws_size,
                              hipStream_t stream)
{
    const float* x  = (const float*)d_in[0];
    const float* ke = (const float*)d_in[1];
    const float* Wq = (const float*)d_in[2];
    const float* bq = (const float*)d_in[3];
    const float* Wk = (const float*)d_in[4];
    const float* bk = (const float*)d_in[5];
    const float* Wv = (const float*)d_in[6];
    const float* bv = (const float*)d_in[7];
    const float* Wo = (const float*)d_in[8];
    const float* bo = (const float*)d_in[9];
    float* out = (float*)d_out;

    // fixed workspace: Qp,Kp,Vp,ctx (16MB each)
    float* Qp  = (float*)d_ws;
    float* Kp  = Qp + (size_t)4096 * 1024;
    float* Vp  = Kp + (size_t)4096 * 1024;
    float* ctx = Vp + (size_t)4096 * 1024;
    float* Sc  = ctx + (size_t)4096 * 1024;
    const size_t baseBytes  = 4ull * 4096 * 1024 * 4;   // 67,108,864
    const size_t carryBytes = 65536ull * TOPK * 8;      // 16,777,216

    // pick the largest score-spill tier that fits ws
    int bhg = 1, NC = 256;
    {
        struct Tier { int bhg; int nc; };
        const Tier tiers[4] = { {32, 512}, {8, 512}, {2, 512}, {1, 256} };
        for (int i = 0; i < 4; ++i) {
            size_t scB = (size_t)tiers[i].bhg * SEQ * tiers[i].nc * 4;
            if (baseBytes + scB + carryBytes <= ws_size) { bhg = tiers[i].bhg; NC = tiers[i].nc; break; }
        }
    }
    u64* carry = (u64*)((char*)d_ws + baseBytes + (size_t)bhg * SEQ * NC * 4);

    dim3 ggrid(32, 8);
    dim3 gblk(256);

    hipLaunchKernelGGL(gemm_xwt_bias, ggrid, gblk, 0, stream, x,  Wq, bq, Qp);
    hipLaunchKernelGGL(gemm_xwt_bias, ggrid, gblk, 0, stream, ke, Wk, bk, Kp);
    hipLaunchKernelGGL(gemm_xwt_bias, ggrid, gblk, 0, stream, ke, Wv, bv, Vp);

    const int passes = NKNOW / NC;
    for (int bh0 = 0; bh0 < 32; bh0 += bhg) {
        for (int p = 0; p < passes; ++p) {
            hipLaunchKernelGGL(scores_gemm, dim3(SEQ / 128, NC / 128, bhg), gblk, 0, stream,
                               Qp, Kp, Sc, p, NC, bh0);
            hipLaunchKernelGGL(topk_pass, dim3(bhg * SEQ / 4), gblk, 0, stream,
                               Sc, carry, Vp, ctx, p, NC, (p > 0) ? 1 : 0,
                               (p == passes - 1) ? 1 : 0, bh0);
        }
    }

    hipLaunchKernelGGL(gemm_xwt_bias, ggrid, gblk, 0, stream, ctx, Wo, bo, out);
}

// Round 3
// 1301.018 us; speedup vs baseline: 6.3550x; 1.6433x over previous
//
#include <hip/hip_runtime.h>
#include <hip/hip_bf16.h>
#include <math.h>

typedef unsigned long long u64;
typedef unsigned int u32;

#define BATCH   2
#define SEQ     2048
#define NKNOW   2048
#define DMODEL  1024
#define NHEADS  16
#define HDIM    64
#define TOPK    32
// SCALE = sqrt(64) = 8 -> multiply scores by 0.125f

// ---------------------------------------------------------------------------
// GEMM: Y[4096,1024] = X[4096,1024] @ W[1024,1024]^T + bias   (fp32)
// 128x128 tile, BK=16, 256 threads, 8x8 micro. (unchanged)
// ---------------------------------------------------------------------------
__global__ __launch_bounds__(256) void gemm_xwt_bias(
    const float* __restrict__ X, const float* __restrict__ W,
    const float* __restrict__ bias, float* __restrict__ Y)
{
    __shared__ float As[16][132];
    __shared__ float Bs[16][132];

    const int t  = threadIdx.x;
    const int m0 = blockIdx.x * 128;
    const int n0 = blockIdx.y * 128;

    const int lm = t >> 2;
    const int lk = (t & 3) << 2;

    const int tx = t & 15;
    const int ty = t >> 4;

    float acc[8][8];
#pragma unroll
    for (int i = 0; i < 8; ++i)
#pragma unroll
        for (int j = 0; j < 8; ++j) acc[i][j] = 0.f;

    for (int k0 = 0; k0 < 1024; k0 += 16) {
        float4 a0 = *(const float4*)(X + (size_t)(m0 + lm) * 1024 + k0 + lk);
        float4 a1 = *(const float4*)(X + (size_t)(m0 + lm + 64) * 1024 + k0 + lk);
        float4 b0 = *(const float4*)(W + (size_t)(n0 + lm) * 1024 + k0 + lk);
        float4 b1 = *(const float4*)(W + (size_t)(n0 + lm + 64) * 1024 + k0 + lk);
        __syncthreads();
        As[lk + 0][lm] = a0.x; As[lk + 1][lm] = a0.y; As[lk + 2][lm] = a0.z; As[lk + 3][lm] = a0.w;
        As[lk + 0][lm + 64] = a1.x; As[lk + 1][lm + 64] = a1.y; As[lk + 2][lm + 64] = a1.z; As[lk + 3][lm + 64] = a1.w;
        Bs[lk + 0][lm] = b0.x; Bs[lk + 1][lm] = b0.y; Bs[lk + 2][lm] = b0.z; Bs[lk + 3][lm] = b0.w;
        Bs[lk + 0][lm + 64] = b1.x; Bs[lk + 1][lm + 64] = b1.y; Bs[lk + 2][lm + 64] = b1.z; Bs[lk + 3][lm + 64] = b1.w;
        __syncthreads();
#pragma unroll
        for (int k = 0; k < 16; ++k) {
            float a[8], b[8];
            *(float4*)(a)     = *(const float4*)&As[k][ty * 8];
            *(float4*)(a + 4) = *(const float4*)&As[k][ty * 8 + 4];
            *(float4*)(b)     = *(const float4*)&Bs[k][tx * 4];
            *(float4*)(b + 4) = *(const float4*)&Bs[k][64 + tx * 4];
#pragma unroll
            for (int i = 0; i < 8; ++i)
#pragma unroll
                for (int j = 0; j < 8; ++j)
                    acc[i][j] = fmaf(a[i], b[j], acc[i][j]);
        }
    }

    float4 bv0 = *(const float4*)(bias + n0 + tx * 4);
    float4 bv1 = *(const float4*)(bias + n0 + 64 + tx * 4);
#pragma unroll
    for (int i = 0; i < 8; ++i) {
        size_t row = (size_t)(m0 + ty * 8 + i) * 1024;
        float4 r0, r1;
        r0.x = acc[i][0] + bv0.x; r0.y = acc[i][1] + bv0.y;
        r0.z = acc[i][2] + bv0.z; r0.w = acc[i][3] + bv0.w;
        r1.x = acc[i][4] + bv1.x; r1.y = acc[i][5] + bv1.y;
        r1.z = acc[i][6] + bv1.z; r1.w = acc[i][7] + bv1.w;
        *(float4*)(Y + row + n0 + tx * 4)      = r0;
        *(float4*)(Y + row + n0 + 64 + tx * 4) = r1;
    }
}

// ---------------------------------------------------------------------------
// Scores chunk GEMM: Sc[bhl, s, nn] = Q[s,:] . K[nn,:] * 0.125  per (b,h).
// 128x128 tile, K=64 single stage, tiles transposed in LDS (64KB).
// ---------------------------------------------------------------------------
__global__ __launch_bounds__(256) void scores_gemm(
    const float* __restrict__ Qp, const float* __restrict__ Kp,
    float* __restrict__ Sc, int NC, int bh0)
{
    __shared__ float As[64][128];
    __shared__ float Bs[64][128];

    const int t   = threadIdx.x;
    const int s0  = blockIdx.x * 128;
    const int nn0 = blockIdx.y * 128;
    const int bhl = blockIdx.z;
    const int bh  = bh0 + bhl;
    const int b   = bh >> 4, h = bh & 15;

    {
        const int g  = t & 3;
        const int r0 = t >> 2;
#pragma unroll
        for (int it = 0; it < 2; ++it) {
            const int r = r0 + 64 * it;
            const float* srcQ = Qp + ((size_t)b * SEQ + s0 + r) * DMODEL + h * HDIM + g * 16;
            const float* srcK = Kp + ((size_t)b * NKNOW + nn0 + r) * DMODEL + h * HDIM + g * 16;
#pragma unroll
            for (int u = 0; u < 4; ++u) {
                float4 v = *(const float4*)(srcQ + u * 4);
                const int d = g * 16 + u * 4;
                As[d + 0][r] = v.x; As[d + 1][r] = v.y; As[d + 2][r] = v.z; As[d + 3][r] = v.w;
            }
#pragma unroll
            for (int u = 0; u < 4; ++u) {
                float4 v = *(const float4*)(srcK + u * 4);
                const int d = g * 16 + u * 4;
                Bs[d + 0][r] = v.x; Bs[d + 1][r] = v.y; Bs[d + 2][r] = v.z; Bs[d + 3][r] = v.w;
            }
        }
    }
    __syncthreads();

    const int tx = t & 15, ty = t >> 4;
    float acc[8][8];
#pragma unroll
    for (int i = 0; i < 8; ++i)
#pragma unroll
        for (int j = 0; j < 8; ++j) acc[i][j] = 0.f;

#pragma unroll 4
    for (int k = 0; k < 64; ++k) {
        float a[8], bb[8];
        *(float4*)(a)      = *(const float4*)&As[k][ty * 8];
        *(float4*)(a + 4)  = *(const float4*)&As[k][ty * 8 + 4];
        *(float4*)(bb)     = *(const float4*)&Bs[k][tx * 4];
        *(float4*)(bb + 4) = *(const float4*)&Bs[k][64 + tx * 4];
#pragma unroll
        for (int i = 0; i < 8; ++i)
#pragma unroll
            for (int j = 0; j < 8; ++j)
                acc[i][j] = fmaf(a[i], bb[j], acc[i][j]);
    }

#pragma unroll
    for (int i = 0; i < 8; ++i) {
        float* dst = Sc + ((size_t)bhl * SEQ + s0 + ty * 8 + i) * NC + nn0;
        float4 r0, r1;
        r0.x = acc[i][0] * 0.125f; r0.y = acc[i][1] * 0.125f;
        r0.z = acc[i][2] * 0.125f; r0.w = acc[i][3] * 0.125f;
        r1.x = acc[i][4] * 0.125f; r1.y = acc[i][5] * 0.125f;
        r1.z = acc[i][6] * 0.125f; r1.w = acc[i][7] * 0.125f;
        *(float4*)(dst + tx * 4)      = r0;
        *(float4*)(dst + 64 + tx * 4) = r1;
    }
}

// ---------------------------------------------------------------------------
// Single-pass exact top-32 + softmax + V-gather. One WAVE per (b,h,s) row.
// Bucket-select on linear value buckets finds the exact 32nd-largest u64 key
// (key = mkey(score)<<32 | (2047-col): distinct, jax tie semantics); the
// selected SET {key >= T64} is all that matters (softmax+gather is
// permutation-invariant). Intra-wave LDS ordering: DS pipe is in-order per
// wave (same guarantee R1's kernel used); wave_barrier() pins the compiler.
// ---------------------------------------------------------------------------
__device__ __forceinline__ u32 mkey_of(float v) {
    u32 u = __float_as_uint(v);
    return (u & 0x80000000u) ? ~u : (u | 0x80000000u);
}
__device__ __forceinline__ u64 pk64(float v, int col) {
    return (((u64)mkey_of(v)) << 32) | (u32)(2047 - col);
}

__global__ __launch_bounds__(256) void topk_radix(
    const float* __restrict__ Sc, const float* __restrict__ Vp,
    float* __restrict__ ctx, int bh0)
{
    __shared__ u32 binsAll[4][256];
    __shared__ u64 candAll[4][64];
    __shared__ u64 selAll[4][32];

    const int t = threadIdx.x, w = t >> 6, l = t & 63;
    const int Rl  = blockIdx.x * 4 + w;
    const int bhl = Rl >> 11, s = Rl & 2047;
    const int bh  = bh0 + bhl;
    const int b   = bh >> 4, h = bh & 15;

    u32* bins = binsAll[w];
    u64* cand = candAll[w];
    u64* sel  = selAll[w];

    // ---- load 32 scores; col(i) = (i>>2)*256 + l*4 + (i&3) ----
    float v[32];
    const float* srow = Sc + (size_t)Rl * 2048;
#pragma unroll
    for (int j = 0; j < 8; ++j) {
        float4 f = *(const float4*)(srow + j * 256 + l * 4);
        v[4 * j + 0] = f.x; v[4 * j + 1] = f.y;
        v[4 * j + 2] = f.z; v[4 * j + 3] = f.w;
    }

    // ---- row max (softmax max == top-1, always selected) ----
    float m = v[0];
#pragma unroll
    for (int i = 1; i < 32; ++i) m = fmaxf(m, v[i]);
#pragma unroll
    for (int d2 = 1; d2 < 64; d2 <<= 1) m = fmaxf(m, __shfl_xor(m, d2, 64));

    // ---- bucket-select the exact 32nd-largest u64 key ----
    float lo = m - 8.0f, width = 8.0f;
    u32 cmask = 0xFFFFFFFFu;
    u32 need  = 32;
    u64 T64   = 0;
    int found = 0;

    for (int attempt = 0; attempt < 6 && !found; ++attempt) {
        const float scale = 256.0f / width;

        *(uint4*)&bins[4 * l] = make_uint4(0u, 0u, 0u, 0u);
        __builtin_amdgcn_wave_barrier();

        u32 bidxArr[8];
#pragma unroll
        for (int q = 0; q < 8; ++q) bidxArr[q] = 0;
#pragma unroll
        for (int i = 0; i < 32; ++i) {
            if ((cmask >> i) & 1u) {
                int bi = (int)((v[i] - lo) * scale);
                bi = bi < 0 ? 0 : (bi > 255 ? 255 : bi);
                atomicAdd(&bins[bi], 1u);
                bidxArr[i >> 2] |= (u32)bi << ((i & 3) * 8);
            }
        }
        __builtin_amdgcn_wave_barrier();

        // suffix scan: lane l covers buckets 4l..4l+3
        uint4 c4 = *(const uint4*)&bins[4 * l];
        u32 tl  = c4.x + c4.y + c4.z + c4.w;
        u32 suf = tl;
#pragma unroll
        for (int d2 = 1; d2 < 64; d2 <<= 1) {
            u32 o = __shfl_down(suf, d2, 64);
            suf += (l + d2 < 64) ? o : 0u;
        }
        u32 above = suf - tl;           // sum over lanes > l
        u32 s3 = above + c4.w;
        u32 s2 = s3 + c4.z;
        u32 s1 = s2 + c4.y;
        u32 s0 = s1 + c4.x;

        bool has = (s0 >= need) && (above < need);
        int dloc = 0; u32 needloc = 0; int Cloc = 0;
        if (has) {
            if      (s3 >= need) { dloc = 4 * l + 3; needloc = need - above; Cloc = (int)c4.w; }
            else if (s2 >= need) { dloc = 4 * l + 2; needloc = need - s3;    Cloc = (int)c4.z; }
            else if (s1 >= need) { dloc = 4 * l + 1; needloc = need - s2;    Cloc = (int)c4.y; }
            else                 { dloc = 4 * l;     needloc = need - s1;    Cloc = (int)c4.x; }
        }
        u64 bal = __ballot(has);
        int src = (int)__ffsll(bal) - 1;
        int d     = __shfl(dloc, src, 64);
        u32 need2 = (u32)__shfl((int)needloc, src, 64);
        int C     = __shfl(Cloc, src, 64);

        if (C <= 64) {
            // compact class-d candidates (full u64 keys), rank-resolve exactly
            u32 cb = 0;
#pragma unroll
            for (int i = 0; i < 32; ++i) {
                int bi = (int)((bidxArr[i >> 2] >> ((i & 3) * 8)) & 255u);
                bool inb = (((cmask >> i) & 1u) != 0u) && (bi == d);
                u64 b2 = __ballot(inb);
                if (inb) {
                    u32 slot = cb + (u32)__popcll(b2 & ((1ull << l) - 1ull));
                    if (slot < 64) {
                        int col = ((i >> 2) << 8) + (l << 2) + (i & 3);
                        cand[slot] = pk64(v[i], col);
                    }
                }
                cb += (u32)__popcll(b2);
            }
            __builtin_amdgcn_wave_barrier();

            u64 myk = (l < C) ? cand[l] : 0ull;
            int rank = 0;
            for (int j = 0; j < C; ++j) rank += (cand[j] > myk) ? 1 : 0;
            bool isT = (l < C) && (rank == (int)need2 - 1);
            u64 balT = __ballot(isT);
            int srcT = (int)__ffsll(balT) - 1;
            T64 = __shfl(myk, srcT, 64);
            found = 1;
        } else {
            // refine: restrict to class d, adjust range
            need = need2;
            u32 nm = 0;
#pragma unroll
            for (int i = 0; i < 32; ++i) {
                int bi = (int)((bidxArr[i >> 2] >> ((i & 3) * 8)) & 255u);
                if ((((cmask >> i) & 1u) != 0u) && (bi == d)) nm |= 1u << i;
            }
            cmask = nm;
            const float bw = width * (1.0f / 256.0f);
            if (d > 0) { lo = lo + (float)d * bw; width = bw; }
            else       { float edge = lo + bw; width = width * 4.0f; lo = edge - width; }
        }
    }

    // ---- compact the selected 32 (score,col), ballot-ordered ----
    u32 cb = 0;
#pragma unroll
    for (int i = 0; i < 32; ++i) {
        int col = ((i >> 2) << 8) + (l << 2) + (i & 3);
        bool sb = pk64(v[i], col) >= T64;
        u64 b2 = __ballot(sb);
        if (sb) {
            u32 slot = cb + (u32)__popcll(b2 & ((1ull << l) - 1ull));
            if (slot < 32) sel[slot] = (((u64)__float_as_uint(v[i])) << 32) | (u32)col;
        }
        cb += (u32)__popcll(b2);
    }
    __builtin_amdgcn_wave_barrier();

    // ---- softmax: one exp per lane (lanes 0..31), Z via wave reduce ----
    float ej = 0.0f;
    if (l < 32) {
        u64 pc = sel[l];
        float sc = __uint_as_float((u32)(pc >> 32));
        ej = __expf(sc - m);
        sel[l] = (((u64)__float_as_uint(ej)) << 32) | (u32)(pc & 0xFFFFFFFFu);
    }
    __builtin_amdgcn_wave_barrier();
    float Z = ej;
#pragma unroll
    for (int d2 = 1; d2 < 64; d2 <<= 1) Z += __shfl_xor(Z, d2, 64);
    const float invZ = 1.0f / Z;

    // ---- V gather: lane = head dim, coalesced 256B per selected row ----
    float acc = 0.0f;
    for (int j = 0; j < 32; ++j) {
        u64 pc = sel[j];
        float e = __uint_as_float((u32)(pc >> 32));
        u32 colj = (u32)(pc & 0xFFFFFFFFu);
        acc = fmaf(e * invZ, Vp[((size_t)b * NKNOW + colj) * DMODEL + h * HDIM + l], acc);
    }
    ctx[((size_t)b * SEQ + s) * DMODEL + h * HDIM + l] = acc;
}

// ---------------------------------------------------------------------------
extern "C" void kernel_launch(void* const* d_in, const int* in_sizes, int n_in,
                              void* d_out, int out_size, void* d_ws, size_t ws_size,
                              hipStream_t stream)
{
    const float* x  = (const float*)d_in[0];
    const float* ke = (const float*)d_in[1];
    const float* Wq = (const float*)d_in[2];
    const float* bq = (const float*)d_in[3];
    const float* Wk = (const float*)d_in[4];
    const float* bk = (const float*)d_in[5];
    const float* Wv = (const float*)d_in[6];
    const float* bv = (const float*)d_in[7];
    const float* Wo = (const float*)d_in[8];
    const float* bo = (const float*)d_in[9];
    float* out = (float*)d_out;

    float* Qp  = (float*)d_ws;
    float* Kp  = Qp + (size_t)4096 * 1024;
    float* Vp  = Kp + (size_t)4096 * 1024;
    float* ctx = Vp + (size_t)4096 * 1024;
    float* Sc  = ctx + (size_t)4096 * 1024;
    const size_t baseBytes = 4ull * 4096 * 1024 * 4;

    // largest bh-chunk whose full-row score spill fits
    int bhg = 1;
    {
        const int tiers[4] = {16, 8, 4, 1};
        for (int i = 0; i < 4; ++i) {
            size_t scB = (size_t)tiers[i] * SEQ * NKNOW * 4;
            if (baseBytes + scB <= ws_size) { bhg = tiers[i]; break; }
        }
    }

    dim3 ggrid(32, 8);
    dim3 gblk(256);

    hipLaunchKernelGGL(gemm_xwt_bias, ggrid, gblk, 0, stream, x,  Wq, bq, Qp);
    hipLaunchKernelGGL(gemm_xwt_bias, ggrid, gblk, 0, stream, ke, Wk, bk, Kp);
    hipLaunchKernelGGL(gemm_xwt_bias, ggrid, gblk, 0, stream, ke, Wv, bv, Vp);

    for (int bh0 = 0; bh0 < 32; bh0 += bhg) {
        hipLaunchKernelGGL(scores_gemm, dim3(SEQ / 128, NKNOW / 128, bhg), gblk, 0, stream,
                           Qp, Kp, Sc, NKNOW, bh0);
        hipLaunchKernelGGL(topk_radix, dim3(bhg * SEQ / 4), gblk, 0, stream,
                           Sc, Vp, ctx, bh0);
    }

    hipLaunchKernelGGL(gemm_xwt_bias, ggrid, gblk, 0, stream, ctx, Wo, bo, out);
}

// Round 6
// 878.965 us; speedup vs baseline: 9.4065x; 1.4802x over previous
//
#include <hip/hip_runtime.h>
#include <math.h>

typedef unsigned long long u64;
typedef unsigned int u32;
typedef unsigned short ush;
typedef __attribute__((ext_vector_type(8))) short short8;   // 8 bf16 (4 VGPRs)
typedef __attribute__((ext_vector_type(4))) float f32x4;    // MFMA C/D frag

#define BATCH   2
#define SEQ     2048
#define NKNOW   2048
#define DMODEL  1024
#define NHEADS  16
#define HDIM    64
#define TOPK    32
#define MSEL    44      // candidate count: gap(rank32->rank44)~0.14 >> bf16 score err
// SCALE = sqrt(64) = 8 -> multiply scores by 0.125f

#define MFMA16(A, B, C) __builtin_amdgcn_mfma_f32_16x16x32_bf16(A, B, C, 0, 0, 0)

__device__ __forceinline__ ush f2bf(float x) {            // round-to-nearest-even
    u32 u = __float_as_uint(x);
    return (ush)((u + 0x7FFFu + ((u >> 16) & 1u)) >> 16);
}
__device__ __forceinline__ float bf2f(ush b) { return __uint_as_float(((u32)b) << 16); }

// ---------------------------------------------------------------------------
// fp32 GEMM (R2-proven, selection-grade): Y = X @ W^T + bias. 128x128, BK=16.
// ---------------------------------------------------------------------------
__global__ __launch_bounds__(256) void gemm_xwt_bias(
    const float* __restrict__ X, const float* __restrict__ W,
    const float* __restrict__ bias, float* __restrict__ Y)
{
    __shared__ float As[16][132];
    __shared__ float Bs[16][132];

    const int t  = threadIdx.x;
    const int m0 = blockIdx.x * 128;
    const int n0 = blockIdx.y * 128;

    const int lm = t >> 2;
    const int lk = (t & 3) << 2;
    const int tx = t & 15;
    const int ty = t >> 4;

    float acc[8][8];
#pragma unroll
    for (int i = 0; i < 8; ++i)
#pragma unroll
        for (int j = 0; j < 8; ++j) acc[i][j] = 0.f;

    for (int k0 = 0; k0 < 1024; k0 += 16) {
        float4 a0 = *(const float4*)(X + (size_t)(m0 + lm) * 1024 + k0 + lk);
        float4 a1 = *(const float4*)(X + (size_t)(m0 + lm + 64) * 1024 + k0 + lk);
        float4 b0 = *(const float4*)(W + (size_t)(n0 + lm) * 1024 + k0 + lk);
        float4 b1 = *(const float4*)(W + (size_t)(n0 + lm + 64) * 1024 + k0 + lk);
        __syncthreads();
        As[lk + 0][lm] = a0.x; As[lk + 1][lm] = a0.y; As[lk + 2][lm] = a0.z; As[lk + 3][lm] = a0.w;
        As[lk + 0][lm + 64] = a1.x; As[lk + 1][lm + 64] = a1.y; As[lk + 2][lm + 64] = a1.z; As[lk + 3][lm + 64] = a1.w;
        Bs[lk + 0][lm] = b0.x; Bs[lk + 1][lm] = b0.y; Bs[lk + 2][lm] = b0.z; Bs[lk + 3][lm] = b0.w;
        Bs[lk + 0][lm + 64] = b1.x; Bs[lk + 1][lm + 64] = b1.y; Bs[lk + 2][lm + 64] = b1.z; Bs[lk + 3][lm + 64] = b1.w;
        __syncthreads();
#pragma unroll
        for (int k = 0; k < 16; ++k) {
            float a[8], b[8];
            *(float4*)(a)     = *(const float4*)&As[k][ty * 8];
            *(float4*)(a + 4) = *(const float4*)&As[k][ty * 8 + 4];
            *(float4*)(b)     = *(const float4*)&Bs[k][tx * 4];
            *(float4*)(b + 4) = *(const float4*)&Bs[k][64 + tx * 4];
#pragma unroll
            for (int i = 0; i < 8; ++i)
#pragma unroll
                for (int j = 0; j < 8; ++j)
                    acc[i][j] = fmaf(a[i], b[j], acc[i][j]);
        }
    }

    float4 bv0 = *(const float4*)(bias + n0 + tx * 4);
    float4 bv1 = *(const float4*)(bias + n0 + 64 + tx * 4);
#pragma unroll
    for (int i = 0; i < 8; ++i) {
        size_t row = (size_t)(m0 + ty * 8 + i) * 1024;
        float4 r0, r1;
        r0.x = acc[i][0] + bv0.x; r0.y = acc[i][1] + bv0.y;
        r0.z = acc[i][2] + bv0.z; r0.w = acc[i][3] + bv0.w;
        r1.x = acc[i][4] + bv1.x; r1.y = acc[i][5] + bv1.y;
        r1.z = acc[i][6] + bv1.z; r1.w = acc[i][7] + bv1.w;
        *(float4*)(Y + row + n0 + tx * 4)      = r0;
        *(float4*)(Y + row + n0 + 64 + tx * 4) = r1;
    }
}

// ---------------------------------------------------------------------------
// 2-way split fp32 -> (hi, lo) bf16.  hi+lo ~ x to 2^-18 (V/O path).
// ---------------------------------------------------------------------------
__global__ __launch_bounds__(256) void split_bf16(
    const float* __restrict__ in, ush* __restrict__ oh, ush* __restrict__ ol, int n)
{
    int i = (blockIdx.x * 256 + threadIdx.x) * 4;
    if (i >= n) return;
    float4 v = *(const float4*)(in + i);
    ush h0 = f2bf(v.x), h1 = f2bf(v.y), h2 = f2bf(v.z), h3 = f2bf(v.w);
    ushort4 hv; hv.x = h0; hv.y = h1; hv.z = h2; hv.w = h3;
    ushort4 lv;
    lv.x = f2bf(v.x - bf2f(h0)); lv.y = f2bf(v.y - bf2f(h1));
    lv.z = f2bf(v.z - bf2f(h2)); lv.w = f2bf(v.w - bf2f(h3));
    *(ushort4*)(oh + i) = hv;
    *(ushort4*)(ol + i) = lv;
}

// ---------------------------------------------------------------------------
// plain fp32 -> bf16 convert (for approx-score Q/K).
// ---------------------------------------------------------------------------
__global__ __launch_bounds__(256) void conv_bf16(
    const float* __restrict__ in, ush* __restrict__ o, int n)
{
    int i = (blockIdx.x * 256 + threadIdx.x) * 4;
    if (i >= n) return;
    float4 v = *(const float4*)(in + i);
    ushort4 hv;
    hv.x = f2bf(v.x); hv.y = f2bf(v.y); hv.z = f2bf(v.z); hv.w = f2bf(v.w);
    *(ushort4*)(o + i) = hv;
}

// ---------------------------------------------------------------------------
// 3-term split-bf16 MFMA GEMM (2^-18-grade; V and O projections ONLY —
// magnitude path, provably no effect on selection). Tile 64x128, BK=64.
// ---------------------------------------------------------------------------
__global__ __launch_bounds__(256) void gemm_mfma_split(
    const ush* __restrict__ Ah, const ush* __restrict__ Al,
    const ush* __restrict__ Bh, const ush* __restrict__ Bl,
    const float* __restrict__ bias, float* __restrict__ Yf)
{
    __shared__ ush sAh[4096], sAl[4096];   // 64 rows x 64 k
    __shared__ ush sBh[8192], sBl[8192];   // 128 rows x 64 k

    const int t = threadIdx.x;
    const int w = t >> 6, lane = t & 63;
    const int m0 = blockIdx.x * 64;
    const int n0 = blockIdx.y * 128;

    f32x4 acc[4][2];
#pragma unroll
    for (int i = 0; i < 4; ++i)
#pragma unroll
        for (int j = 0; j < 2; ++j) acc[i][j] = (f32x4){0.f, 0.f, 0.f, 0.f};

    for (int k0 = 0; k0 < 1024; k0 += 64) {
        __syncthreads();
#pragma unroll
        for (int c = t; c < 512; c += 256) {
            int t16 = c >> 7, ks = (c >> 6) & 1, ln = c & 63;
            int row = t16 * 16 + (ln & 15);
            int k8  = ks * 4 + (ln >> 4);
            size_t g = (size_t)(m0 + row) * 1024 + k0 + k8 * 8;
            *(uint4*)&sAh[c * 8] = *(const uint4*)(Ah + g);
            *(uint4*)&sAl[c * 8] = *(const uint4*)(Al + g);
        }
#pragma unroll
        for (int c = t; c < 1024; c += 256) {
            int t16 = c >> 7, ks = (c >> 6) & 1, ln = c & 63;
            int row = t16 * 16 + (ln & 15);
            int k8  = ks * 4 + (ln >> 4);
            size_t g = (size_t)(n0 + row) * 1024 + k0 + k8 * 8;
            *(uint4*)&sBh[c * 8] = *(const uint4*)(Bh + g);
            *(uint4*)&sBl[c * 8] = *(const uint4*)(Bl + g);
        }
        __syncthreads();

#pragma unroll
        for (int ks = 0; ks < 2; ++ks) {
            short8 a_h[4], a_l[4], b_h[2], b_l[2];
#pragma unroll
            for (int i = 0; i < 4; ++i) {
                a_h[i] = *(const short8*)&sAh[((i * 2 + ks) * 64 + lane) * 8];
                a_l[i] = *(const short8*)&sAl[((i * 2 + ks) * 64 + lane) * 8];
            }
#pragma unroll
            for (int j = 0; j < 2; ++j) {
                int nt = w * 2 + j;
                b_h[j] = *(const short8*)&sBh[((nt * 2 + ks) * 64 + lane) * 8];
                b_l[j] = *(const short8*)&sBl[((nt * 2 + ks) * 64 + lane) * 8];
            }
#pragma unroll
            for (int i = 0; i < 4; ++i)
#pragma unroll
                for (int j = 0; j < 2; ++j) {
                    acc[i][j] = MFMA16(a_h[i], b_h[j], acc[i][j]);
                    acc[i][j] = MFMA16(a_h[i], b_l[j], acc[i][j]);
                    acc[i][j] = MFMA16(a_l[i], b_h[j], acc[i][j]);
                }
        }
    }

    const int quad = lane >> 4, c16 = lane & 15;
#pragma unroll
    for (int i = 0; i < 4; ++i)
#pragma unroll
        for (int j = 0; j < 2; ++j) {
            int colg = n0 + (w * 2 + j) * 16 + c16;
            float bia = bias[colg];
#pragma unroll
            for (int r = 0; r < 4; ++r) {
                int rowg = m0 + i * 16 + quad * 4 + r;
                Yf[(size_t)rowg * 1024 + colg] = acc[i][j][r] + bia;
            }
        }
}

// ---------------------------------------------------------------------------
// Approx scores: 1-term plain-bf16 MFMA per (b,h); Sc stored as bf16.
// Only used for CANDIDATE INCLUSION (margin ~0.14 >> bf16 err ~0.01).
// 128x128 tile, K=64 (2 ks steps of 16x16x32).
// ---------------------------------------------------------------------------
__global__ __launch_bounds__(256) void scores_bf16(
    const ush* __restrict__ Qb, const ush* __restrict__ Kb,
    ush* __restrict__ Sc, int bh0)
{
    __shared__ ush sA[8192], sB[8192];   // 128 rows x 64 k each

    const int t = threadIdx.x;
    const int w = t >> 6, lane = t & 63;
    const int s0  = blockIdx.x * 128;
    const int nn0 = blockIdx.y * 128;
    const int bhl = blockIdx.z;
    const int bh  = bh0 + bhl;
    const int b   = bh >> 4, h = bh & 15;

#pragma unroll
    for (int c = t; c < 1024; c += 256) {
        int t16 = c >> 7, ks = (c >> 6) & 1, ln = c & 63;
        int row = t16 * 16 + (ln & 15);
        int k8  = ks * 4 + (ln >> 4);
        size_t gq = ((size_t)b * SEQ + s0 + row) * 1024 + h * 64 + k8 * 8;
        size_t gk = ((size_t)b * NKNOW + nn0 + row) * 1024 + h * 64 + k8 * 8;
        *(uint4*)&sA[c * 8] = *(const uint4*)(Qb + gq);
        *(uint4*)&sB[c * 8] = *(const uint4*)(Kb + gk);
    }
    __syncthreads();

    const int r0t = (w >> 1) * 4, c0t = (w & 1) * 4;
    f32x4 acc[4][4];
#pragma unroll
    for (int i = 0; i < 4; ++i)
#pragma unroll
        for (int j = 0; j < 4; ++j) acc[i][j] = (f32x4){0.f, 0.f, 0.f, 0.f};

#pragma unroll
    for (int ks = 0; ks < 2; ++ks) {
        short8 a[4], bb[4];
#pragma unroll
        for (int i = 0; i < 4; ++i)
            a[i] = *(const short8*)&sA[(((r0t + i) * 2 + ks) * 64 + lane) * 8];
#pragma unroll
        for (int j = 0; j < 4; ++j)
            bb[j] = *(const short8*)&sB[(((c0t + j) * 2 + ks) * 64 + lane) * 8];
#pragma unroll
        for (int i = 0; i < 4; ++i)
#pragma unroll
            for (int j = 0; j < 4; ++j)
                acc[i][j] = MFMA16(a[i], bb[j], acc[i][j]);
    }

    const int quad = lane >> 4, c16 = lane & 15;
#pragma unroll
    for (int i = 0; i < 4; ++i)
#pragma unroll
        for (int j = 0; j < 4; ++j) {
            int colg = nn0 + (c0t + j) * 16 + c16;
#pragma unroll
            for (int r = 0; r < 4; ++r) {
                int rowg = s0 + (r0t + i) * 16 + quad * 4 + r;
                Sc[((size_t)bhl * SEQ + rowg) * 2048 + colg] = f2bf(acc[i][j][r] * 0.125f);
            }
        }
}

// ---------------------------------------------------------------------------
// Top-k with exact rescoring. One WAVE per (b,h,s) row.
// 1) bucket-select the MSEL'th-largest approx key (R2-proven machinery),
// 2) compact MSEL candidate cols, 3) EXACT fp32 rescore (deterministic 64-dot
//    on fp32-VALU Q/K — np-grade), 4) all-pairs exact rank -> top-32,
// 5) softmax(exact) + V gather; ctx written as bf16 hi/lo.
// ---------------------------------------------------------------------------
__device__ __forceinline__ u32 mkey_of(float v) {
    u32 u = __float_as_uint(v);
    return (u & 0x80000000u) ? ~u : (u | 0x80000000u);
}
__device__ __forceinline__ u64 pk64(float v, int col) {
    return (((u64)mkey_of(v)) << 32) | (u32)(2047 - col);
}

__global__ __launch_bounds__(256) void topk_rescore(
    const ush* __restrict__ Scb, const float* __restrict__ Qp,
    const float* __restrict__ Kp, const float* __restrict__ Vp,
    ush* __restrict__ ctxh, ush* __restrict__ ctxl, int bh0)
{
    __shared__ u32 binsAll[4][256];
    __shared__ u64 candAll[4][64];
    __shared__ u32 selcAll[4][64];
    __shared__ u64 selAll[4][32];
    __shared__ float qrowAll[4][64];

    const int t = threadIdx.x, w = t >> 6, l = t & 63;
    const int Rl  = blockIdx.x * 4 + w;
    const int bhl = Rl >> 11, s = Rl & 2047;
    const int bh  = bh0 + bhl;
    const int b   = bh >> 4, h = bh & 15;

    u32* bins = binsAll[w];
    u64* cand = candAll[w];
    u32* selc = selcAll[w];
    u64* sel  = selAll[w];
    float* qrow = qrowAll[w];

    // ---- load 32 approx scores (bf16); col(i) = (i>>3)*512 + l*8 + (i&7) ----
    float v[32];
    const ush* srow = Scb + (size_t)Rl * 2048;
#pragma unroll
    for (int j = 0; j < 4; ++j) {
        ushort4 p0 = *(const ushort4*)(srow + j * 512 + l * 8);
        ushort4 p1 = *(const ushort4*)(srow + j * 512 + l * 8 + 4);
        v[8 * j + 0] = bf2f(p0.x); v[8 * j + 1] = bf2f(p0.y);
        v[8 * j + 2] = bf2f(p0.z); v[8 * j + 3] = bf2f(p0.w);
        v[8 * j + 4] = bf2f(p1.x); v[8 * j + 5] = bf2f(p1.y);
        v[8 * j + 6] = bf2f(p1.z); v[8 * j + 7] = bf2f(p1.w);
    }

    // stage Q row for rescoring (fp32, np-grade)
    qrow[l] = Qp[((size_t)b * SEQ + s) * 1024 + h * 64 + l];

    float m = v[0];
#pragma unroll
    for (int i = 1; i < 32; ++i) m = fmaxf(m, v[i]);
#pragma unroll
    for (int d2 = 1; d2 < 64; d2 <<= 1) m = fmaxf(m, __shfl_xor(m, d2, 64));

    // ---- bucket-select the exact MSEL'th-largest approx u64 key ----
    float lo = m - 8.0f, width = 8.0f;
    u32 cmask = 0xFFFFFFFFu;
    u32 need  = MSEL;
    u64 T64   = 0;
    int found = 0;

    for (int attempt = 0; attempt < 6 && !found; ++attempt) {
        const float scale = 256.0f / width;

        *(uint4*)&bins[4 * l] = make_uint4(0u, 0u, 0u, 0u);
        __builtin_amdgcn_wave_barrier();

        u32 bidxArr[8];
#pragma unroll
        for (int q = 0; q < 8; ++q) bidxArr[q] = 0;
#pragma unroll
        for (int i = 0; i < 32; ++i) {
            if ((cmask >> i) & 1u) {
                int bi = (int)((v[i] - lo) * scale);
                bi = bi < 0 ? 0 : (bi > 255 ? 255 : bi);
                atomicAdd(&bins[bi], 1u);
                bidxArr[i >> 2] |= (u32)bi << ((i & 3) * 8);
            }
        }
        __builtin_amdgcn_wave_barrier();

        uint4 c4 = *(const uint4*)&bins[4 * l];
        u32 tl  = c4.x + c4.y + c4.z + c4.w;
        u32 suf = tl;
#pragma unroll
        for (int d2 = 1; d2 < 64; d2 <<= 1) {
            u32 o = __shfl_down(suf, d2, 64);
            suf += (l + d2 < 64) ? o : 0u;
        }
        u32 above = suf - tl;
        u32 s3 = above + c4.w;
        u32 s2 = s3 + c4.z;
        u32 s1 = s2 + c4.y;
        u32 s0 = s1 + c4.x;

        bool has = (s0 >= need) && (above < need);
        int dloc = 0; u32 needloc = 0; int Cloc = 0;
        if (has) {
            if      (s3 >= need) { dloc = 4 * l + 3; needloc = need - above; Cloc = (int)c4.w; }
            else if (s2 >= need) { dloc = 4 * l + 2; needloc = need - s3;    Cloc = (int)c4.z; }
            else if (s1 >= need) { dloc = 4 * l + 1; needloc = need - s2;    Cloc = (int)c4.y; }
            else                 { dloc = 4 * l;     needloc = need - s1;    Cloc = (int)c4.x; }
        }
        u64 bal = __ballot(has);
        int src = (int)__ffsll(bal) - 1;
        int d     = __shfl(dloc, src, 64);
        u32 need2 = (u32)__shfl((int)needloc, src, 64);
        int C     = __shfl(Cloc, src, 64);

        if (C <= 64) {
            u32 cb = 0;
#pragma unroll
            for (int i = 0; i < 32; ++i) {
                int bi = (int)((bidxArr[i >> 2] >> ((i & 3) * 8)) & 255u);
                bool inb = (((cmask >> i) & 1u) != 0u) && (bi == d);
                u64 b2 = __ballot(inb);
                if (inb) {
                    u32 slot = cb + (u32)__popcll(b2 & ((1ull << l) - 1ull));
                    if (slot < 64) {
                        int col = ((i >> 3) << 9) + (l << 3) + (i & 7);
                        cand[slot] = pk64(v[i], col);
                    }
                }
                cb += (u32)__popcll(b2);
            }
            __builtin_amdgcn_wave_barrier();

            u64 myk = (l < C) ? cand[l] : 0ull;
            int rank = 0;
            for (int j = 0; j < C; ++j) rank += (cand[j] > myk) ? 1 : 0;
            bool isT = (l < C) && (rank == (int)need2 - 1);
            u64 balT = __ballot(isT);
            int srcT = (int)__ffsll(balT) - 1;
            T64 = __shfl(myk, srcT, 64);
            found = 1;
        } else {
            need = need2;
            u32 nm = 0;
#pragma unroll
            for (int i = 0; i < 32; ++i) {
                int bi = (int)((bidxArr[i >> 2] >> ((i & 3) * 8)) & 255u);
                if ((((cmask >> i) & 1u) != 0u) && (bi == d)) nm |= 1u << i;
            }
            cmask = nm;
            const float bw = width * (1.0f / 256.0f);
            if (d > 0) { lo = lo + (float)d * bw; width = bw; }
            else       { float edge = lo + bw; width = width * 4.0f; lo = edge - width; }
        }
    }

    // ---- compact the MSEL candidate cols ----
    u32 cb = 0;
#pragma unroll
    for (int i = 0; i < 32; ++i) {
        int col = ((i >> 3) << 9) + (l << 3) + (i & 7);
        bool sb = pk64(v[i], col) >= T64;
        u64 b2 = __ballot(sb);
        if (sb) {
            u32 slot = cb + (u32)__popcll(b2 & ((1ull << l) - 1ull));
            if (slot < 64) selc[slot] = (u32)col;
        }
        cb += (u32)__popcll(b2);
    }
    __builtin_amdgcn_wave_barrier();

    // ---- EXACT rescore: lane j < MSEL does a deterministic fp32 64-dot ----
    float sx = -3.0e38f;
    u32 mycol = 0;
    if (l < MSEL) {
        mycol = selc[l];
        const float* kr = Kp + ((size_t)b * NKNOW + mycol) * 1024 + h * 64;
        float p0 = 0.f, p1 = 0.f, p2 = 0.f, p3 = 0.f;
#pragma unroll
        for (int d = 0; d < 64; d += 4) {
            float4 kv = *(const float4*)(kr + d);
            float4 qv = *(const float4*)&qrow[d];
            p0 = fmaf(qv.x, kv.x, p0);
            p1 = fmaf(qv.y, kv.y, p1);
            p2 = fmaf(qv.z, kv.z, p2);
            p3 = fmaf(qv.w, kv.w, p3);
        }
        sx = ((p0 + p1) + (p2 + p3)) * 0.125f;
    }

    // ---- exact rank among MSEL (jax tie semantics via pk64) ----
    cand[l] = (l < MSEL) ? pk64(sx, (int)mycol) : 0ull;
    __builtin_amdgcn_wave_barrier();
    u64 myk = cand[l];
    int rank = 0;
#pragma unroll 4
    for (int j = 0; j < MSEL; ++j) rank += (cand[j] > myk) ? 1 : 0;
    const bool win = (l < MSEL) && (rank < TOPK);

    // ---- softmax over exact top-32 ----
    float mx = win ? sx : -3.0e38f;
#pragma unroll
    for (int d2 = 1; d2 < 64; d2 <<= 1) mx = fmaxf(mx, __shfl_xor(mx, d2, 64));
    float e = win ? __expf(sx - mx) : 0.0f;
    float Z = e;
#pragma unroll
    for (int d2 = 1; d2 < 64; d2 <<= 1) Z += __shfl_xor(Z, d2, 64);
    const float invZ = 1.0f / Z;

    u64 bw2 = __ballot(win);
    if (win) {
        u32 slot = (u32)__popcll(bw2 & ((1ull << l) - 1ull));
        sel[slot] = (((u64)__float_as_uint(e)) << 32) | mycol;
    }
    __builtin_amdgcn_wave_barrier();

    // ---- V gather: lane = head dim, coalesced 256B per selected row ----
    float acc = 0.0f;
    for (int j = 0; j < TOPK; ++j) {
        u64 pc = sel[j];
        float ej = __uint_as_float((u32)(pc >> 32));
        u32 colj = (u32)(pc & 0xFFFFFFFFu);
        acc = fmaf(ej * invZ, Vp[((size_t)b * NKNOW + colj) * 1024 + h * 64 + l], acc);
    }
    size_t oidx = ((size_t)b * SEQ + s) * 1024 + h * 64 + l;
    ush hh = f2bf(acc);
    ctxh[oidx] = hh;
    ctxl[oidx] = f2bf(acc - bf2f(hh));
}

// ---------------------------------------------------------------------------
extern "C" void kernel_launch(void* const* d_in, const int* in_sizes, int n_in,
                              void* d_out, int out_size, void* d_ws, size_t ws_size,
                              hipStream_t stream)
{
    const float* x  = (const float*)d_in[0];
    const float* ke = (const float*)d_in[1];
    const float* Wq = (const float*)d_in[2];
    const float* bq = (const float*)d_in[3];
    const float* Wk = (const float*)d_in[4];
    const float* bk = (const float*)d_in[5];
    const float* Wv = (const float*)d_in[6];
    const float* bv = (const float*)d_in[7];
    const float* Wo = (const float*)d_in[8];
    const float* bo = (const float*)d_in[9];
    float* out = (float*)d_out;

    const size_t NB = (size_t)4096 * 1024;
    const size_t NW = (size_t)1024 * 1024;

    char* p = (char*)d_ws;
    float *Qp = (float*)p;  p += NB * 4;
    float *Kp = (float*)p;  p += NB * 4;
    float *Vp = (float*)p;  p += NB * 4;
    ush *Qb  = (ush*)p;     p += NB * 2;
    ush *Kb  = (ush*)p;     p += NB * 2;
    ush *keh = (ush*)p;     p += NB * 2;
    ush *kel = (ush*)p;     p += NB * 2;
    ush *Wvh = (ush*)p;     p += NW * 2;
    ush *Wvl = (ush*)p;     p += NW * 2;
    ush *Woh = (ush*)p;     p += NW * 2;
    ush *Wol = (ush*)p;     p += NW * 2;
    ush *ctxh = (ush*)p;    p += NB * 2;
    ush *ctxl = (ush*)p;    p += NB * 2;
    ush *Sc = (ush*)p;
    const size_t fixedBytes = (size_t)(p - (char*)d_ws);

    int bhg = 1;
    {
        const int tiers[6] = {32, 16, 8, 4, 2, 1};
        for (int i = 0; i < 6; ++i) {
            size_t scB = (size_t)tiers[i] * SEQ * NKNOW * 2;   // bf16 spill
            if (fixedBytes + scB <= ws_size) { bhg = tiers[i]; break; }
        }
    }

    dim3 blk(256);

    // weight/input splits for V/O MFMA path
    hipLaunchKernelGGL(split_bf16, dim3((int)(NB / 1024)), blk, 0, stream, ke, keh, kel, (int)NB);
    hipLaunchKernelGGL(split_bf16, dim3((int)(NW / 1024)), blk, 0, stream, Wv, Wvh, Wvl, (int)NW);
    hipLaunchKernelGGL(split_bf16, dim3((int)(NW / 1024)), blk, 0, stream, Wo, Woh, Wol, (int)NW);

    // Q,K projections: fp32 VALU (np-grade, R2-proven)
    dim3 g32(32, 8);
    hipLaunchKernelGGL(gemm_xwt_bias, g32, blk, 0, stream, x,  Wq, bq, Qp);
    hipLaunchKernelGGL(gemm_xwt_bias, g32, blk, 0, stream, ke, Wk, bk, Kp);

    // V projection: 3-term MFMA (magnitude-only path)
    dim3 gmf(64, 8);
    hipLaunchKernelGGL(gemm_mfma_split, gmf, blk, 0, stream, keh, kel, Wvh, Wvl, bv, Vp);

    // bf16 copies of Q,K for the approx score pass
    hipLaunchKernelGGL(conv_bf16, dim3((int)(NB / 1024)), blk, 0, stream, Qp, Qb, (int)NB);
    hipLaunchKernelGGL(conv_bf16, dim3((int)(NB / 1024)), blk, 0, stream, Kp, Kb, (int)NB);

    for (int bh0 = 0; bh0 < 32; bh0 += bhg) {
        hipLaunchKernelGGL(scores_bf16, dim3(SEQ / 128, NKNOW / 128, bhg), blk, 0, stream,
                           Qb, Kb, Sc, bh0);
        hipLaunchKernelGGL(topk_rescore, dim3(bhg * SEQ / 4), blk, 0, stream,
                           Sc, Qp, Kp, Vp, ctxh, ctxl, bh0);
    }

    // O projection: 3-term MFMA -> fp32 out
    hipLaunchKernelGGL(gemm_mfma_split, gmf, blk, 0, stream, ctxh, ctxl, Woh, Wol, bo, out);
}

// Round 7
// 780.553 us; speedup vs baseline: 10.5925x; 1.1261x over previous
//
#include <hip/hip_runtime.h>
#include <math.h>

typedef unsigned long long u64;
typedef unsigned int u32;
typedef unsigned short ush;
typedef __attribute__((ext_vector_type(8))) short short8;   // 8 bf16 (4 VGPRs)
typedef __attribute__((ext_vector_type(4))) float f32x4;    // MFMA C/D frag

#define BATCH   2
#define SEQ     2048
#define NKNOW   2048
#define DMODEL  1024
#define NHEADS  16
#define HDIM    64
#define TOPK    32
#define CPAD    44     // accept threshold when cum >= 44 (same margin class as R5's MSEL=44)

#define MFMA16(A, B, C) __builtin_amdgcn_mfma_f32_16x16x32_bf16(A, B, C, 0, 0, 0)

__device__ __forceinline__ ush f2bf(float x) {            // round-to-nearest-even
    u32 u = __float_as_uint(x);
    return (ush)((u + 0x7FFFu + ((u >> 16) & 1u)) >> 16);
}
__device__ __forceinline__ float bf2f(ush b) { return __uint_as_float(((u32)b) << 16); }

// ---------------------------------------------------------------------------
// fp32 GEMM v2: Y = X @ W^T + bias. 64x128 tile, BK=32, grid 512 (2 blk/CU).
// Per-output-element FMA chain is k-sequential 0..1023 with one accumulator:
// BITWISE-IDENTICAL output to the R5 128x128 kernel (flip-luck preserved).
// Optional bf16 copy written in epilogue (folds conv_bf16).
// ---------------------------------------------------------------------------
__global__ __launch_bounds__(256) void gemm_f32_v2(
    const float* __restrict__ X, const float* __restrict__ W,
    const float* __restrict__ bias, float* __restrict__ Y, ush* __restrict__ Yb)
{
    __shared__ float As[32][66];    // [k][row], 64 rows
    __shared__ float Bs[32][130];   // [k][col], 128 cols

    const int t  = threadIdx.x;
    const int m0 = blockIdx.x * 64;
    const int n0 = blockIdx.y * 128;

    const int ra = t >> 2, ka = (t & 3) * 8;    // A staging: row, k-offset
    const int rb = t >> 1, kb = (t & 1) * 16;   // B staging

    const int ty = t >> 5;        // rows ty*8..+7
    const int tx = t & 31;        // cols tx*4..+3

    float acc[8][4];
#pragma unroll
    for (int i = 0; i < 8; ++i)
#pragma unroll
        for (int j = 0; j < 4; ++j) acc[i][j] = 0.f;

    for (int k0 = 0; k0 < 1024; k0 += 32) {
        float4 a0 = *(const float4*)(X + (size_t)(m0 + ra) * 1024 + k0 + ka);
        float4 a1 = *(const float4*)(X + (size_t)(m0 + ra) * 1024 + k0 + ka + 4);
        float4 b0 = *(const float4*)(W + (size_t)(n0 + rb) * 1024 + k0 + kb);
        float4 b1 = *(const float4*)(W + (size_t)(n0 + rb) * 1024 + k0 + kb + 4);
        float4 b2 = *(const float4*)(W + (size_t)(n0 + rb) * 1024 + k0 + kb + 8);
        float4 b3 = *(const float4*)(W + (size_t)(n0 + rb) * 1024 + k0 + kb + 12);
        __syncthreads();
        As[ka + 0][ra] = a0.x; As[ka + 1][ra] = a0.y; As[ka + 2][ra] = a0.z; As[ka + 3][ra] = a0.w;
        As[ka + 4][ra] = a1.x; As[ka + 5][ra] = a1.y; As[ka + 6][ra] = a1.z; As[ka + 7][ra] = a1.w;
        Bs[kb + 0][rb] = b0.x; Bs[kb + 1][rb] = b0.y; Bs[kb + 2][rb] = b0.z; Bs[kb + 3][rb] = b0.w;
        Bs[kb + 4][rb] = b1.x; Bs[kb + 5][rb] = b1.y; Bs[kb + 6][rb] = b1.z; Bs[kb + 7][rb] = b1.w;
        Bs[kb + 8][rb] = b2.x; Bs[kb + 9][rb] = b2.y; Bs[kb +10][rb] = b2.z; Bs[kb +11][rb] = b2.w;
        Bs[kb +12][rb] = b3.x; Bs[kb +13][rb] = b3.y; Bs[kb +14][rb] = b3.z; Bs[kb +15][rb] = b3.w;
        __syncthreads();
#pragma unroll 4
        for (int k = 0; k < 32; ++k) {
            float a[8], b[4];
            *(float4*)(a)     = *(const float4*)&As[k][ty * 8];
            *(float4*)(a + 4) = *(const float4*)&As[k][ty * 8 + 4];
            *(float4*)(b)     = *(const float4*)&Bs[k][tx * 4];
#pragma unroll
            for (int i = 0; i < 8; ++i)
#pragma unroll
                for (int j = 0; j < 4; ++j)
                    acc[i][j] = fmaf(a[i], b[j], acc[i][j]);
        }
    }

    float4 bv = *(const float4*)(bias + n0 + tx * 4);
    const float bb[4] = {bv.x, bv.y, bv.z, bv.w};
#pragma unroll
    for (int i = 0; i < 8; ++i) {
        size_t row = (size_t)(m0 + ty * 8 + i) * 1024;
        float4 r;
        r.x = acc[i][0] + bb[0]; r.y = acc[i][1] + bb[1];
        r.z = acc[i][2] + bb[2]; r.w = acc[i][3] + bb[3];
        *(float4*)(Y + row + n0 + tx * 4) = r;
        if (Yb) {
            ushort4 h;
            h.x = f2bf(r.x); h.y = f2bf(r.y); h.z = f2bf(r.z); h.w = f2bf(r.w);
            *(ushort4*)(Yb + row + n0 + tx * 4) = h;
        }
    }
}

// ---------------------------------------------------------------------------
// 2-way split fp32 -> (hi, lo) bf16.  hi+lo ~ x to 2^-18 (V/O path).
// ---------------------------------------------------------------------------
__global__ __launch_bounds__(256) void split_bf16(
    const float* __restrict__ in, ush* __restrict__ oh, ush* __restrict__ ol, int n)
{
    int i = (blockIdx.x * 256 + threadIdx.x) * 4;
    if (i >= n) return;
    float4 v = *(const float4*)(in + i);
    ush h0 = f2bf(v.x), h1 = f2bf(v.y), h2 = f2bf(v.z), h3 = f2bf(v.w);
    ushort4 hv; hv.x = h0; hv.y = h1; hv.z = h2; hv.w = h3;
    ushort4 lv;
    lv.x = f2bf(v.x - bf2f(h0)); lv.y = f2bf(v.y - bf2f(h1));
    lv.z = f2bf(v.z - bf2f(h2)); lv.w = f2bf(v.w - bf2f(h3));
    *(ushort4*)(oh + i) = hv;
    *(ushort4*)(ol + i) = lv;
}

// ---------------------------------------------------------------------------
// 3-term split-bf16 MFMA GEMM (2^-18-grade; V and O projections only).
// ---------------------------------------------------------------------------
__global__ __launch_bounds__(256) void gemm_mfma_split(
    const ush* __restrict__ Ah, const ush* __restrict__ Al,
    const ush* __restrict__ Bh, const ush* __restrict__ Bl,
    const float* __restrict__ bias, float* __restrict__ Yf)
{
    __shared__ ush sAh[4096], sAl[4096];   // 64 rows x 64 k
    __shared__ ush sBh[8192], sBl[8192];   // 128 rows x 64 k

    const int t = threadIdx.x;
    const int w = t >> 6, lane = t & 63;
    const int m0 = blockIdx.x * 64;
    const int n0 = blockIdx.y * 128;

    f32x4 acc[4][2];
#pragma unroll
    for (int i = 0; i < 4; ++i)
#pragma unroll
        for (int j = 0; j < 2; ++j) acc[i][j] = (f32x4){0.f, 0.f, 0.f, 0.f};

    for (int k0 = 0; k0 < 1024; k0 += 64) {
        __syncthreads();
#pragma unroll
        for (int c = t; c < 512; c += 256) {
            int t16 = c >> 7, ks = (c >> 6) & 1, ln = c & 63;
            int row = t16 * 16 + (ln & 15);
            int k8  = ks * 4 + (ln >> 4);
            size_t g = (size_t)(m0 + row) * 1024 + k0 + k8 * 8;
            *(uint4*)&sAh[c * 8] = *(const uint4*)(Ah + g);
            *(uint4*)&sAl[c * 8] = *(const uint4*)(Al + g);
        }
#pragma unroll
        for (int c = t; c < 1024; c += 256) {
            int t16 = c >> 7, ks = (c >> 6) & 1, ln = c & 63;
            int row = t16 * 16 + (ln & 15);
            int k8  = ks * 4 + (ln >> 4);
            size_t g = (size_t)(n0 + row) * 1024 + k0 + k8 * 8;
            *(uint4*)&sBh[c * 8] = *(const uint4*)(Bh + g);
            *(uint4*)&sBl[c * 8] = *(const uint4*)(Bl + g);
        }
        __syncthreads();

#pragma unroll
        for (int ks = 0; ks < 2; ++ks) {
            short8 a_h[4], a_l[4], b_h[2], b_l[2];
#pragma unroll
            for (int i = 0; i < 4; ++i) {
                a_h[i] = *(const short8*)&sAh[((i * 2 + ks) * 64 + lane) * 8];
                a_l[i] = *(const short8*)&sAl[((i * 2 + ks) * 64 + lane) * 8];
            }
#pragma unroll
            for (int j = 0; j < 2; ++j) {
                int nt = w * 2 + j;
                b_h[j] = *(const short8*)&sBh[((nt * 2 + ks) * 64 + lane) * 8];
                b_l[j] = *(const short8*)&sBl[((nt * 2 + ks) * 64 + lane) * 8];
            }
#pragma unroll
            for (int i = 0; i < 4; ++i)
#pragma unroll
                for (int j = 0; j < 2; ++j) {
                    acc[i][j] = MFMA16(a_h[i], b_h[j], acc[i][j]);
                    acc[i][j] = MFMA16(a_h[i], b_l[j], acc[i][j]);
                    acc[i][j] = MFMA16(a_l[i], b_h[j], acc[i][j]);
                }
        }
    }

    const int quad = lane >> 4, c16 = lane & 15;
#pragma unroll
    for (int i = 0; i < 4; ++i)
#pragma unroll
        for (int j = 0; j < 2; ++j) {
            int colg = n0 + (w * 2 + j) * 16 + c16;
            float bia = bias[colg];
#pragma unroll
            for (int r = 0; r < 4; ++r) {
                int rowg = m0 + i * 16 + quad * 4 + r;
                Yf[(size_t)rowg * 1024 + colg] = acc[i][j][r] + bia;
            }
        }
}

// ---------------------------------------------------------------------------
// Approx scores: 1-term plain-bf16 MFMA per (b,h); Sc stored as bf16.
// ---------------------------------------------------------------------------
__global__ __launch_bounds__(256) void scores_bf16(
    const ush* __restrict__ Qb, const ush* __restrict__ Kb,
    ush* __restrict__ Sc, int bh0)
{
    __shared__ ush sA[8192], sB[8192];

    const int t = threadIdx.x;
    const int w = t >> 6, lane = t & 63;
    const int s0  = blockIdx.x * 128;
    const int nn0 = blockIdx.y * 128;
    const int bhl = blockIdx.z;
    const int bh  = bh0 + bhl;
    const int b   = bh >> 4, h = bh & 15;

#pragma unroll
    for (int c = t; c < 1024; c += 256) {
        int t16 = c >> 7, ks = (c >> 6) & 1, ln = c & 63;
        int row = t16 * 16 + (ln & 15);
        int k8  = ks * 4 + (ln >> 4);
        size_t gq = ((size_t)b * SEQ + s0 + row) * 1024 + h * 64 + k8 * 8;
        size_t gk = ((size_t)b * NKNOW + nn0 + row) * 1024 + h * 64 + k8 * 8;
        *(uint4*)&sA[c * 8] = *(const uint4*)(Qb + gq);
        *(uint4*)&sB[c * 8] = *(const uint4*)(Kb + gk);
    }
    __syncthreads();

    const int r0t = (w >> 1) * 4, c0t = (w & 1) * 4;
    f32x4 acc[4][4];
#pragma unroll
    for (int i = 0; i < 4; ++i)
#pragma unroll
        for (int j = 0; j < 4; ++j) acc[i][j] = (f32x4){0.f, 0.f, 0.f, 0.f};

#pragma unroll
    for (int ks = 0; ks < 2; ++ks) {
        short8 a[4], bb[4];
#pragma unroll
        for (int i = 0; i < 4; ++i)
            a[i] = *(const short8*)&sA[(((r0t + i) * 2 + ks) * 64 + lane) * 8];
#pragma unroll
        for (int j = 0; j < 4; ++j)
            bb[j] = *(const short8*)&sB[(((c0t + j) * 2 + ks) * 64 + lane) * 8];
#pragma unroll
        for (int i = 0; i < 4; ++i)
#pragma unroll
            for (int j = 0; j < 4; ++j)
                acc[i][j] = MFMA16(a[i], bb[j], acc[i][j]);
    }

    const int quad = lane >> 4, c16 = lane & 15;
#pragma unroll
    for (int i = 0; i < 4; ++i)
#pragma unroll
        for (int j = 0; j < 4; ++j) {
            int colg = nn0 + (c0t + j) * 16 + c16;
#pragma unroll
            for (int r = 0; r < 4; ++r) {
                int rowg = s0 + (r0t + i) * 16 + quad * 4 + r;
                Sc[((size_t)bhl * SEQ + rowg) * 2048 + colg] = f2bf(acc[i][j][r] * 0.125f);
            }
        }
}

// ---------------------------------------------------------------------------
// Top-k v2: bucket-edge threshold -> cursor compact -> exact fp32 rescore ->
// exact all-pairs rank -> softmax + V gather.  One WAVE per (b,h,s) row.
// Correctness: T = min bucket-edge with cum<=64; cum>=44 accepted (refined
// otherwise). Candidates {approx >= T} are a superset of the true top-32
// (edge <= approx_rank44 <= exact_rank32 - margin); exact pk64 re-rank then
// yields the SAME top-32 set as R5 -> output unchanged.
// ---------------------------------------------------------------------------
__device__ __forceinline__ u32 mkey_of(float v) {
    u32 u = __float_as_uint(v);
    return (u & 0x80000000u) ? ~u : (u | 0x80000000u);
}
__device__ __forceinline__ u64 pk64(float v, int col) {
    return (((u64)mkey_of(v)) << 32) | (u32)(2047 - col);
}

__global__ __launch_bounds__(256) void topk_rescore2(
    const ush* __restrict__ Scb, const float* __restrict__ Qp,
    const float* __restrict__ Kp, const float* __restrict__ Vp,
    ush* __restrict__ ctxh, ush* __restrict__ ctxl, int bh0)
{
    __shared__ u32 binsAll[4][256];
    __shared__ u64 keysAll[4][64];
    __shared__ u32 selcAll[4][64];
    __shared__ u64 selAll[4][32];
    __shared__ float qrowAll[4][64];
    __shared__ u32 cntAll[4];

    const int t = threadIdx.x, w = t >> 6, l = t & 63;
    const int Rl  = blockIdx.x * 4 + w;
    const int bhl = Rl >> 11, s = Rl & 2047;
    const int bh  = bh0 + bhl;
    const int b   = bh >> 4, h = bh & 15;

    u32* bins = binsAll[w];
    u64* keys = keysAll[w];
    u32* selc = selcAll[w];
    u64* sel  = selAll[w];
    float* qrow = qrowAll[w];

    // ---- load 32 approx scores (bf16); col(i) = (i>>3)*512 + l*8 + (i&7) ----
    float v[32];
    const ush* srow = Scb + (size_t)Rl * 2048;
#pragma unroll
    for (int j = 0; j < 4; ++j) {
        ushort4 p0 = *(const ushort4*)(srow + j * 512 + l * 8);
        ushort4 p1 = *(const ushort4*)(srow + j * 512 + l * 8 + 4);
        v[8 * j + 0] = bf2f(p0.x); v[8 * j + 1] = bf2f(p0.y);
        v[8 * j + 2] = bf2f(p0.z); v[8 * j + 3] = bf2f(p0.w);
        v[8 * j + 4] = bf2f(p1.x); v[8 * j + 5] = bf2f(p1.y);
        v[8 * j + 6] = bf2f(p1.z); v[8 * j + 7] = bf2f(p1.w);
    }

    qrow[l] = Qp[((size_t)b * SEQ + s) * 1024 + h * 64 + l];

    float m = v[0];
#pragma unroll
    for (int i = 1; i < 32; ++i) m = fmaxf(m, v[i]);
#pragma unroll
    for (int d2 = 1; d2 < 64; d2 <<= 1) m = fmaxf(m, __shfl_xor(m, d2, 64));

    // ---- bucket-edge threshold: min edge with cum <= 64 (refine if cum < 44) ----
    float lo = m - 8.0f, width = 8.0f;
    u32 base = 0;
    int havePrev = 0; float pLo = 0.f, pScale = 0.f; int pBkt = 0;
    float T = m - 8.0f;

    for (int att = 0; att < 3; ++att) {
        const float scale = 256.0f / width;

        *(uint4*)&bins[4 * l] = make_uint4(0u, 0u, 0u, 0u);
        __builtin_amdgcn_wave_barrier();

#pragma unroll
        for (int i = 0; i < 32; ++i) {
            float vi = v[i];
            bool in = (vi >= lo);
            if (havePrev) {
                int pb = (int)fminf((vi - pLo) * pScale, 255.0f);
                in = (vi >= pLo) && (pb == pBkt);
            }
            if (in) {
                int bi = (int)fminf((vi - lo) * scale, 255.0f);
                bi = bi < 0 ? 0 : bi;
                atomicAdd(&bins[bi], 1u);
            }
        }
        __builtin_amdgcn_wave_barrier();

        uint4 c4 = *(const uint4*)&bins[4 * l];
        u32 tl  = c4.x + c4.y + c4.z + c4.w;
        u32 suf = tl;
#pragma unroll
        for (int d2 = 1; d2 < 64; d2 <<= 1) {
            u32 o = __shfl_down(suf, d2, 64);
            suf += (l + d2 < 64) ? o : 0u;
        }
        u32 above = suf - tl;                    // sum over lanes > l
        u32 cs3 = base + above + c4.w;           // cum at edge 4l+3
        u32 cs2 = cs3 + c4.z;
        u32 cs1 = cs2 + c4.y;
        u32 cs0 = cs1 + c4.x;

        bool has = (cs3 <= 64);
        int eloc; u32 nloc;
        if      (cs0 <= 64) { eloc = 4 * l;     nloc = cs0; }
        else if (cs1 <= 64) { eloc = 4 * l + 1; nloc = cs1; }
        else if (cs2 <= 64) { eloc = 4 * l + 2; nloc = cs2; }
        else                { eloc = 4 * l + 3; nloc = cs3; }

        u64 bal = __ballot(has);
        const float bw = width * (1.0f / 256.0f);
        if (bal == 0ull) {
            // >64 values share the top bucket: refine into bucket 255
            havePrev = 1; pLo = lo; pScale = scale; pBkt = 255;
            lo = lo + 255.0f * bw; width = bw;
            T = lo;
            continue;
        }
        int src  = (int)__ffsll(bal) - 1;
        int eS   = __shfl(eloc, src, 64);
        u32 nAt  = (u32)__shfl((int)nloc, src, 64);
        T = lo + (float)eS * bw;
        if (nAt >= CPAD || eS == 0 || att == 2) break;
        // refine into bucket eS-1 for more candidates
        havePrev = 1; pLo = lo; pScale = scale; pBkt = eS - 1;
        base = nAt;
        lo = lo + (float)(eS - 1) * bw; width = bw;
    }

    // ---- cursor compaction of candidates {v >= T} (cap 64) ----
    if (l == 0) cntAll[w] = 0u;
    __builtin_amdgcn_wave_barrier();
#pragma unroll
    for (int i = 0; i < 32; ++i) {
        if (v[i] >= T) {
            u32 slot = atomicAdd(&cntAll[w], 1u);
            if (slot < 64) {
                int col = ((i >> 3) << 9) + (l << 3) + (i & 7);
                selc[slot] = (u32)col;
            }
        }
    }
    __builtin_amdgcn_wave_barrier();
    int C = (int)cntAll[w]; C = C > 64 ? 64 : C;

    // ---- EXACT rescore (identical order to R5: stride-4 accumulators) ----
    float sx = -3.0e38f;
    u32 mycol = 0;
    if (l < C) {
        mycol = selc[l];
        const float* kr = Kp + ((size_t)b * NKNOW + mycol) * 1024 + h * 64;
        float p0 = 0.f, p1 = 0.f, p2 = 0.f, p3 = 0.f;
#pragma unroll
        for (int d = 0; d < 64; d += 4) {
            float4 kv = *(const float4*)(kr + d);
            float4 qv = *(const float4*)&qrow[d];
            p0 = fmaf(qv.x, kv.x, p0);
            p1 = fmaf(qv.y, kv.y, p1);
            p2 = fmaf(qv.z, kv.z, p2);
            p3 = fmaf(qv.w, kv.w, p3);
        }
        sx = ((p0 + p1) + (p2 + p3)) * 0.125f;
    }

    // ---- exact all-pairs rank over C candidates (pk64: jax tie semantics) ----
    keys[l] = (l < C) ? pk64(sx, (int)mycol) : 0ull;
    __builtin_amdgcn_wave_barrier();
    u64 myk = keys[l];
    int rank = 0;
#pragma unroll 8
    for (int j = 0; j < 64; ++j) rank += (keys[j] > myk) ? 1 : 0;
    const bool win = (l < C) && (rank < TOPK);

    // ---- softmax over exact top-32 ----
    float mx = win ? sx : -3.0e38f;
#pragma unroll
    for (int d2 = 1; d2 < 64; d2 <<= 1) mx = fmaxf(mx, __shfl_xor(mx, d2, 64));
    float e = win ? __expf(sx - mx) : 0.0f;
    float Z = e;
#pragma unroll
    for (int d2 = 1; d2 < 64; d2 <<= 1) Z += __shfl_xor(Z, d2, 64);
    const float invZ = 1.0f / Z;

    u64 bw2 = __ballot(win);
    if (win) {
        u32 slot = (u32)__popcll(bw2 & ((1ull << l) - 1ull));
        sel[slot] = (((u64)__float_as_uint(e)) << 32) | mycol;
    }
    __builtin_amdgcn_wave_barrier();

    // ---- V gather: lane = head dim, coalesced 256B per selected row ----
    float acc = 0.0f;
    for (int j = 0; j < TOPK; ++j) {
        u64 pc = sel[j];
        float ej = __uint_as_float((u32)(pc >> 32));
        u32 colj = (u32)(pc & 0xFFFFFFFFu);
        acc = fmaf(ej * invZ, Vp[((size_t)b * NKNOW + colj) * 1024 + h * 64 + l], acc);
    }
    size_t oidx = ((size_t)b * SEQ + s) * 1024 + h * 64 + l;
    ush hh = f2bf(acc);
    ctxh[oidx] = hh;
    ctxl[oidx] = f2bf(acc - bf2f(hh));
}

// ---------------------------------------------------------------------------
extern "C" void kernel_launch(void* const* d_in, const int* in_sizes, int n_in,
                              void* d_out, int out_size, void* d_ws, size_t ws_size,
                              hipStream_t stream)
{
    const float* x  = (const float*)d_in[0];
    const float* ke = (const float*)d_in[1];
    const float* Wq = (const float*)d_in[2];
    const float* bq = (const float*)d_in[3];
    const float* Wk = (const float*)d_in[4];
    const float* bk = (const float*)d_in[5];
    const float* Wv = (const float*)d_in[6];
    const float* bv = (const float*)d_in[7];
    const float* Wo = (const float*)d_in[8];
    const float* bo = (const float*)d_in[9];
    float* out = (float*)d_out;

    const size_t NB = (size_t)4096 * 1024;
    const size_t NW = (size_t)1024 * 1024;

    char* p = (char*)d_ws;
    float *Qp = (float*)p;  p += NB * 4;
    float *Kp = (float*)p;  p += NB * 4;
    float *Vp = (float*)p;  p += NB * 4;
    ush *Qb  = (ush*)p;     p += NB * 2;
    ush *Kb  = (ush*)p;     p += NB * 2;
    ush *keh = (ush*)p;     p += NB * 2;
    ush *kel = (ush*)p;     p += NB * 2;
    ush *Wvh = (ush*)p;     p += NW * 2;
    ush *Wvl = (ush*)p;     p += NW * 2;
    ush *Woh = (ush*)p;     p += NW * 2;
    ush *Wol = (ush*)p;     p += NW * 2;
    ush *ctxh = (ush*)p;    p += NB * 2;
    ush *ctxl = (ush*)p;    p += NB * 2;
    ush *Sc = (ush*)p;
    const size_t fixedBytes = (size_t)(p - (char*)d_ws);

    int bhg = 1;
    {
        const int tiers[6] = {32, 16, 8, 4, 2, 1};
        for (int i = 0; i < 6; ++i) {
            size_t scB = (size_t)tiers[i] * SEQ * NKNOW * 2;   // bf16 spill
            if (fixedBytes + scB <= ws_size) { bhg = tiers[i]; break; }
        }
    }

    dim3 blk(256);

    // weight/input splits for V/O MFMA path
    hipLaunchKernelGGL(split_bf16, dim3((int)(NB / 1024)), blk, 0, stream, ke, keh, kel, (int)NB);
    hipLaunchKernelGGL(split_bf16, dim3((int)(NW / 1024)), blk, 0, stream, Wv, Wvh, Wvl, (int)NW);
    hipLaunchKernelGGL(split_bf16, dim3((int)(NW / 1024)), blk, 0, stream, Wo, Woh, Wol, (int)NW);

    // Q,K projections: fp32 VALU v2 (bitwise-identical output to R5) + fused bf16 copy
    dim3 g64(64, 8);
    hipLaunchKernelGGL(gemm_f32_v2, g64, blk, 0, stream, x,  Wq, bq, Qp, Qb);
    hipLaunchKernelGGL(gemm_f32_v2, g64, blk, 0, stream, ke, Wk, bk, Kp, Kb);

    // V projection: 3-term MFMA (magnitude-only path)
    dim3 gmf(64, 8);
    hipLaunchKernelGGL(gemm_mfma_split, gmf, blk, 0, stream, keh, kel, Wvh, Wvl, bv, Vp);

    for (int bh0 = 0; bh0 < 32; bh0 += bhg) {
        hipLaunchKernelGGL(scores_bf16, dim3(SEQ / 128, NKNOW / 128, bhg), blk, 0, stream,
                           Qb, Kb, Sc, bh0);
        hipLaunchKernelGGL(topk_rescore2, dim3(bhg * SEQ / 4), blk, 0, stream,
                           Sc, Qp, Kp, Vp, ctxh, ctxl, bh0);
    }

    // O projection: 3-term MFMA -> fp32 out
    hipLaunchKernelGGL(gemm_mfma_split, gmf, blk, 0, stream, ctxh, ctxl, Woh, Wol, bo, out);
}

// Round 8
// 776.703 us; speedup vs baseline: 10.6450x; 1.0050x over previous
//
#include <hip/hip_runtime.h>
#include <math.h>

typedef unsigned long long u64;
typedef unsigned int u32;
typedef unsigned short ush;
typedef __attribute__((ext_vector_type(8))) short short8;   // 8 bf16 (4 VGPRs)
typedef __attribute__((ext_vector_type(4))) float f32x4;    // MFMA C/D frag

#define BATCH   2
#define SEQ     2048
#define NKNOW   2048
#define DMODEL  1024
#define NHEADS  16
#define HDIM    64
#define TOPK    32
#define CPAD    44     // accept threshold when cum >= 44 (R5/R6-proven margin)

#define MFMA16(A, B, C) __builtin_amdgcn_mfma_f32_16x16x32_bf16(A, B, C, 0, 0, 0)

__device__ __forceinline__ ush f2bf(float x) {            // round-to-nearest-even
    u32 u = __float_as_uint(x);
    return (ush)((u + 0x7FFFu + ((u >> 16) & 1u)) >> 16);
}
__device__ __forceinline__ float bf2f(ush b) { return __uint_as_float(((u32)b) << 16); }

// ---------------------------------------------------------------------------
// Merged Q/K fp32 GEMM: z=0 -> (X0,W0,b0), z=1 -> (X1,W1,b1). 64x128, BK=32.
// 1024 blocks -> 4 blocks/CU (vs R6's 2): occupancy doubles, same per-element
// k-sequential single-accumulator FMA chain -> BITWISE-IDENTICAL Q/K to R6.
// bf16 copy fused in epilogue.
// ---------------------------------------------------------------------------
__global__ __launch_bounds__(256) void gemm_f32_qk(
    const float* __restrict__ X0, const float* __restrict__ W0,
    const float* __restrict__ b0, float* __restrict__ Y0, ush* __restrict__ Yb0,
    const float* __restrict__ X1, const float* __restrict__ W1,
    const float* __restrict__ b1, float* __restrict__ Y1, ush* __restrict__ Yb1)
{
    __shared__ float As[32][66];    // [k][row], 64 rows
    __shared__ float Bs[32][130];   // [k][col], 128 cols

    const int z = blockIdx.z;
    const float* X   = z ? X1 : X0;
    const float* W   = z ? W1 : W0;
    const float* bia = z ? b1 : b0;
    float* Y  = z ? Y1 : Y0;
    ush*   Yb = z ? Yb1 : Yb0;

    const int t  = threadIdx.x;
    const int m0 = blockIdx.x * 64;
    const int n0 = blockIdx.y * 128;

    const int ra = t >> 2, ka = (t & 3) * 8;    // A staging: row, k-offset
    const int rb = t >> 1, kb = (t & 1) * 16;   // B staging

    const int ty = t >> 5;        // rows ty*8..+7
    const int tx = t & 31;        // cols tx*4..+3

    float acc[8][4];
#pragma unroll
    for (int i = 0; i < 8; ++i)
#pragma unroll
        for (int j = 0; j < 4; ++j) acc[i][j] = 0.f;

    for (int k0 = 0; k0 < 1024; k0 += 32) {
        float4 a0 = *(const float4*)(X + (size_t)(m0 + ra) * 1024 + k0 + ka);
        float4 a1 = *(const float4*)(X + (size_t)(m0 + ra) * 1024 + k0 + ka + 4);
        float4 b0v = *(const float4*)(W + (size_t)(n0 + rb) * 1024 + k0 + kb);
        float4 b1v = *(const float4*)(W + (size_t)(n0 + rb) * 1024 + k0 + kb + 4);
        float4 b2v = *(const float4*)(W + (size_t)(n0 + rb) * 1024 + k0 + kb + 8);
        float4 b3v = *(const float4*)(W + (size_t)(n0 + rb) * 1024 + k0 + kb + 12);
        __syncthreads();
        As[ka + 0][ra] = a0.x; As[ka + 1][ra] = a0.y; As[ka + 2][ra] = a0.z; As[ka + 3][ra] = a0.w;
        As[ka + 4][ra] = a1.x; As[ka + 5][ra] = a1.y; As[ka + 6][ra] = a1.z; As[ka + 7][ra] = a1.w;
        Bs[kb + 0][rb] = b0v.x; Bs[kb + 1][rb] = b0v.y; Bs[kb + 2][rb] = b0v.z; Bs[kb + 3][rb] = b0v.w;
        Bs[kb + 4][rb] = b1v.x; Bs[kb + 5][rb] = b1v.y; Bs[kb + 6][rb] = b1v.z; Bs[kb + 7][rb] = b1v.w;
        Bs[kb + 8][rb] = b2v.x; Bs[kb + 9][rb] = b2v.y; Bs[kb +10][rb] = b2v.z; Bs[kb +11][rb] = b2v.w;
        Bs[kb +12][rb] = b3v.x; Bs[kb +13][rb] = b3v.y; Bs[kb +14][rb] = b3v.z; Bs[kb +15][rb] = b3v.w;
        __syncthreads();
#pragma unroll 4
        for (int k = 0; k < 32; ++k) {
            float a[8], b[4];
            *(float4*)(a)     = *(const float4*)&As[k][ty * 8];
            *(float4*)(a + 4) = *(const float4*)&As[k][ty * 8 + 4];
            *(float4*)(b)     = *(const float4*)&Bs[k][tx * 4];
#pragma unroll
            for (int i = 0; i < 8; ++i)
#pragma unroll
                for (int j = 0; j < 4; ++j)
                    acc[i][j] = fmaf(a[i], b[j], acc[i][j]);
        }
    }

    float4 bv = *(const float4*)(bia + n0 + tx * 4);
    const float bb[4] = {bv.x, bv.y, bv.z, bv.w};
#pragma unroll
    for (int i = 0; i < 8; ++i) {
        size_t row = (size_t)(m0 + ty * 8 + i) * 1024;
        float4 r;
        r.x = acc[i][0] + bb[0]; r.y = acc[i][1] + bb[1];
        r.z = acc[i][2] + bb[2]; r.w = acc[i][3] + bb[3];
        *(float4*)(Y + row + n0 + tx * 4) = r;
        ushort4 hh;
        hh.x = f2bf(r.x); hh.y = f2bf(r.y); hh.z = f2bf(r.z); hh.w = f2bf(r.w);
        *(ushort4*)(Yb + row + n0 + tx * 4) = hh;
    }
}

// ---------------------------------------------------------------------------
// fp32 -> bf16 convert.
// ---------------------------------------------------------------------------
__global__ __launch_bounds__(256) void conv_bf16(
    const float* __restrict__ in, ush* __restrict__ o, int n)
{
    int i = (blockIdx.x * 256 + threadIdx.x) * 4;
    if (i >= n) return;
    float4 v = *(const float4*)(in + i);
    ushort4 hv;
    hv.x = f2bf(v.x); hv.y = f2bf(v.y); hv.z = f2bf(v.z); hv.w = f2bf(v.w);
    *(ushort4*)(o + i) = hv;
}

// ---------------------------------------------------------------------------
// 2-way split fp32 -> (hi, lo) bf16 (O-projection weights only).
// ---------------------------------------------------------------------------
__global__ __launch_bounds__(256) void split_bf16(
    const float* __restrict__ in, ush* __restrict__ oh, ush* __restrict__ ol, int n)
{
    int i = (blockIdx.x * 256 + threadIdx.x) * 4;
    if (i >= n) return;
    float4 v = *(const float4*)(in + i);
    ush h0 = f2bf(v.x), h1 = f2bf(v.y), h2 = f2bf(v.z), h3 = f2bf(v.w);
    ushort4 hv; hv.x = h0; hv.y = h1; hv.z = h2; hv.w = h3;
    ushort4 lv;
    lv.x = f2bf(v.x - bf2f(h0)); lv.y = f2bf(v.y - bf2f(h1));
    lv.z = f2bf(v.z - bf2f(h2)); lv.w = f2bf(v.w - bf2f(h3));
    *(ushort4*)(oh + i) = hv;
    *(ushort4*)(ol + i) = lv;
}

// ---------------------------------------------------------------------------
// 1-term plain-bf16 MFMA GEMM (V projection: magnitude-only, flip-free).
// Tile 64x128, BK=64. fp32 out + bias.
// ---------------------------------------------------------------------------
__global__ __launch_bounds__(256) void gemm_mfma_1t(
    const ush* __restrict__ Ab, const ush* __restrict__ Bb,
    const float* __restrict__ bias, float* __restrict__ Yf)
{
    __shared__ ush sA[4096];   // 64 rows x 64 k
    __shared__ ush sB[8192];   // 128 rows x 64 k

    const int t = threadIdx.x;
    const int w = t >> 6, lane = t & 63;
    const int m0 = blockIdx.x * 64;
    const int n0 = blockIdx.y * 128;

    f32x4 acc[4][2];
#pragma unroll
    for (int i = 0; i < 4; ++i)
#pragma unroll
        for (int j = 0; j < 2; ++j) acc[i][j] = (f32x4){0.f, 0.f, 0.f, 0.f};

    for (int k0 = 0; k0 < 1024; k0 += 64) {
        __syncthreads();
#pragma unroll
        for (int c = t; c < 512; c += 256) {
            int t16 = c >> 7, ks = (c >> 6) & 1, ln = c & 63;
            int row = t16 * 16 + (ln & 15);
            int k8  = ks * 4 + (ln >> 4);
            size_t g = (size_t)(m0 + row) * 1024 + k0 + k8 * 8;
            *(uint4*)&sA[c * 8] = *(const uint4*)(Ab + g);
        }
#pragma unroll
        for (int c = t; c < 1024; c += 256) {
            int t16 = c >> 7, ks = (c >> 6) & 1, ln = c & 63;
            int row = t16 * 16 + (ln & 15);
            int k8  = ks * 4 + (ln >> 4);
            size_t g = (size_t)(n0 + row) * 1024 + k0 + k8 * 8;
            *(uint4*)&sB[c * 8] = *(const uint4*)(Bb + g);
        }
        __syncthreads();

#pragma unroll
        for (int ks = 0; ks < 2; ++ks) {
            short8 a[4], b[2];
#pragma unroll
            for (int i = 0; i < 4; ++i)
                a[i] = *(const short8*)&sA[((i * 2 + ks) * 64 + lane) * 8];
#pragma unroll
            for (int j = 0; j < 2; ++j) {
                int nt = w * 2 + j;
                b[j] = *(const short8*)&sB[((nt * 2 + ks) * 64 + lane) * 8];
            }
#pragma unroll
            for (int i = 0; i < 4; ++i)
#pragma unroll
                for (int j = 0; j < 2; ++j)
                    acc[i][j] = MFMA16(a[i], b[j], acc[i][j]);
        }
    }

    const int quad = lane >> 4, c16 = lane & 15;
#pragma unroll
    for (int i = 0; i < 4; ++i)
#pragma unroll
        for (int j = 0; j < 2; ++j) {
            int colg = n0 + (w * 2 + j) * 16 + c16;
            float bia = bias[colg];
#pragma unroll
            for (int r = 0; r < 4; ++r) {
                int rowg = m0 + i * 16 + quad * 4 + r;
                Yf[(size_t)rowg * 1024 + colg] = acc[i][j][r] + bia;
            }
        }
}

// ---------------------------------------------------------------------------
// 3-term split-bf16 MFMA GEMM (O projection). Tile 64x128, BK=64.
// ---------------------------------------------------------------------------
__global__ __launch_bounds__(256) void gemm_mfma_split(
    const ush* __restrict__ Ah, const ush* __restrict__ Al,
    const ush* __restrict__ Bh, const ush* __restrict__ Bl,
    const float* __restrict__ bias, float* __restrict__ Yf)
{
    __shared__ ush sAh[4096], sAl[4096];
    __shared__ ush sBh[8192], sBl[8192];

    const int t = threadIdx.x;
    const int w = t >> 6, lane = t & 63;
    const int m0 = blockIdx.x * 64;
    const int n0 = blockIdx.y * 128;

    f32x4 acc[4][2];
#pragma unroll
    for (int i = 0; i < 4; ++i)
#pragma unroll
        for (int j = 0; j < 2; ++j) acc[i][j] = (f32x4){0.f, 0.f, 0.f, 0.f};

    for (int k0 = 0; k0 < 1024; k0 += 64) {
        __syncthreads();
#pragma unroll
        for (int c = t; c < 512; c += 256) {
            int t16 = c >> 7, ks = (c >> 6) & 1, ln = c & 63;
            int row = t16 * 16 + (ln & 15);
            int k8  = ks * 4 + (ln >> 4);
            size_t g = (size_t)(m0 + row) * 1024 + k0 + k8 * 8;
            *(uint4*)&sAh[c * 8] = *(const uint4*)(Ah + g);
            *(uint4*)&sAl[c * 8] = *(const uint4*)(Al + g);
        }
#pragma unroll
        for (int c = t; c < 1024; c += 256) {
            int t16 = c >> 7, ks = (c >> 6) & 1, ln = c & 63;
            int row = t16 * 16 + (ln & 15);
            int k8  = ks * 4 + (ln >> 4);
            size_t g = (size_t)(n0 + row) * 1024 + k0 + k8 * 8;
            *(uint4*)&sBh[c * 8] = *(const uint4*)(Bh + g);
            *(uint4*)&sBl[c * 8] = *(const uint4*)(Bl + g);
        }
        __syncthreads();

#pragma unroll
        for (int ks = 0; ks < 2; ++ks) {
            short8 a_h[4], a_l[4], b_h[2], b_l[2];
#pragma unroll
            for (int i = 0; i < 4; ++i) {
                a_h[i] = *(const short8*)&sAh[((i * 2 + ks) * 64 + lane) * 8];
                a_l[i] = *(const short8*)&sAl[((i * 2 + ks) * 64 + lane) * 8];
            }
#pragma unroll
            for (int j = 0; j < 2; ++j) {
                int nt = w * 2 + j;
                b_h[j] = *(const short8*)&sBh[((nt * 2 + ks) * 64 + lane) * 8];
                b_l[j] = *(const short8*)&sBl[((nt * 2 + ks) * 64 + lane) * 8];
            }
#pragma unroll
            for (int i = 0; i < 4; ++i)
#pragma unroll
                for (int j = 0; j < 2; ++j) {
                    acc[i][j] = MFMA16(a_h[i], b_h[j], acc[i][j]);
                    acc[i][j] = MFMA16(a_h[i], b_l[j], acc[i][j]);
                    acc[i][j] = MFMA16(a_l[i], b_h[j], acc[i][j]);
                }
        }
    }

    const int quad = lane >> 4, c16 = lane & 15;
#pragma unroll
    for (int i = 0; i < 4; ++i)
#pragma unroll
        for (int j = 0; j < 2; ++j) {
            int colg = n0 + (w * 2 + j) * 16 + c16;
            float bia = bias[colg];
#pragma unroll
            for (int r = 0; r < 4; ++r) {
                int rowg = m0 + i * 16 + quad * 4 + r;
                Yf[(size_t)rowg * 1024 + colg] = acc[i][j][r] + bia;
            }
        }
}

// ---------------------------------------------------------------------------
// Approx scores: 1-term plain-bf16 MFMA per (b,h); Sc stored as bf16.
// ---------------------------------------------------------------------------
__global__ __launch_bounds__(256) void scores_bf16(
    const ush* __restrict__ Qb, const ush* __restrict__ Kb,
    ush* __restrict__ Sc, int bh0)
{
    __shared__ ush sA[8192], sB[8192];

    const int t = threadIdx.x;
    const int w = t >> 6, lane = t & 63;
    const int s0  = blockIdx.x * 128;
    const int nn0 = blockIdx.y * 128;
    const int bhl = blockIdx.z;
    const int bh  = bh0 + bhl;
    const int b   = bh >> 4, h = bh & 15;

#pragma unroll
    for (int c = t; c < 1024; c += 256) {
        int t16 = c >> 7, ks = (c >> 6) & 1, ln = c & 63;
        int row = t16 * 16 + (ln & 15);
        int k8  = ks * 4 + (ln >> 4);
        size_t gq = ((size_t)b * SEQ + s0 + row) * 1024 + h * 64 + k8 * 8;
        size_t gk = ((size_t)b * NKNOW + nn0 + row) * 1024 + h * 64 + k8 * 8;
        *(uint4*)&sA[c * 8] = *(const uint4*)(Qb + gq);
        *(uint4*)&sB[c * 8] = *(const uint4*)(Kb + gk);
    }
    __syncthreads();

    const int r0t = (w >> 1) * 4, c0t = (w & 1) * 4;
    f32x4 acc[4][4];
#pragma unroll
    for (int i = 0; i < 4; ++i)
#pragma unroll
        for (int j = 0; j < 4; ++j) acc[i][j] = (f32x4){0.f, 0.f, 0.f, 0.f};

#pragma unroll
    for (int ks = 0; ks < 2; ++ks) {
        short8 a[4], bb[4];
#pragma unroll
        for (int i = 0; i < 4; ++i)
            a[i] = *(const short8*)&sA[(((r0t + i) * 2 + ks) * 64 + lane) * 8];
#pragma unroll
        for (int j = 0; j < 4; ++j)
            bb[j] = *(const short8*)&sB[(((c0t + j) * 2 + ks) * 64 + lane) * 8];
#pragma unroll
        for (int i = 0; i < 4; ++i)
#pragma unroll
            for (int j = 0; j < 4; ++j)
                acc[i][j] = MFMA16(a[i], bb[j], acc[i][j]);
    }

    const int quad = lane >> 4, c16 = lane & 15;
#pragma unroll
    for (int i = 0; i < 4; ++i)
#pragma unroll
        for (int j = 0; j < 4; ++j) {
            int colg = nn0 + (c0t + j) * 16 + c16;
#pragma unroll
            for (int r = 0; r < 4; ++r) {
                int rowg = s0 + (r0t + i) * 16 + quad * 4 + r;
                Sc[((size_t)bhl * SEQ + rowg) * 2048 + colg] = f2bf(acc[i][j][r] * 0.125f);
            }
        }
}

// ---------------------------------------------------------------------------
// Top-k v2 (R6-proven selection logic, unchanged math):
// bucket-edge threshold -> cursor compact -> exact fp32 rescore ->
// exact all-pairs rank (bounded by C) -> softmax + V gather (unrolled x4).
// ---------------------------------------------------------------------------
__device__ __forceinline__ u32 mkey_of(float v) {
    u32 u = __float_as_uint(v);
    return (u & 0x80000000u) ? ~u : (u | 0x80000000u);
}
__device__ __forceinline__ u64 pk64(float v, int col) {
    return (((u64)mkey_of(v)) << 32) | (u32)(2047 - col);
}

__global__ __launch_bounds__(256) void topk_rescore2(
    const ush* __restrict__ Scb, const float* __restrict__ Qp,
    const float* __restrict__ Kp, const float* __restrict__ Vp,
    ush* __restrict__ ctxh, ush* __restrict__ ctxl, int bh0)
{
    __shared__ u32 binsAll[4][256];
    __shared__ u64 keysAll[4][64];
    __shared__ u32 selcAll[4][64];
    __shared__ u64 selAll[4][32];
    __shared__ float qrowAll[4][64];
    __shared__ u32 cntAll[4];

    const int t = threadIdx.x, w = t >> 6, l = t & 63;
    const int Rl  = blockIdx.x * 4 + w;
    const int bhl = Rl >> 11, s = Rl & 2047;
    const int bh  = bh0 + bhl;
    const int b   = bh >> 4, h = bh & 15;

    u32* bins = binsAll[w];
    u64* keys = keysAll[w];
    u32* selc = selcAll[w];
    u64* sel  = selAll[w];
    float* qrow = qrowAll[w];

    // ---- load 32 approx scores (bf16); col(i) = (i>>3)*512 + l*8 + (i&7) ----
    float v[32];
    const ush* srow = Scb + (size_t)Rl * 2048;
#pragma unroll
    for (int j = 0; j < 4; ++j) {
        ushort4 p0 = *(const ushort4*)(srow + j * 512 + l * 8);
        ushort4 p1 = *(const ushort4*)(srow + j * 512 + l * 8 + 4);
        v[8 * j + 0] = bf2f(p0.x); v[8 * j + 1] = bf2f(p0.y);
        v[8 * j + 2] = bf2f(p0.z); v[8 * j + 3] = bf2f(p0.w);
        v[8 * j + 4] = bf2f(p1.x); v[8 * j + 5] = bf2f(p1.y);
        v[8 * j + 6] = bf2f(p1.z); v[8 * j + 7] = bf2f(p1.w);
    }

    qrow[l] = Qp[((size_t)b * SEQ + s) * 1024 + h * 64 + l];

    float m = v[0];
#pragma unroll
    for (int i = 1; i < 32; ++i) m = fmaxf(m, v[i]);
#pragma unroll
    for (int d2 = 1; d2 < 64; d2 <<= 1) m = fmaxf(m, __shfl_xor(m, d2, 64));

    // ---- bucket-edge threshold: min edge with cum <= 64 (refine if cum < 44) ----
    float lo = m - 8.0f, width = 8.0f;
    u32 base = 0;
    int havePrev = 0; float pLo = 0.f, pScale = 0.f; int pBkt = 0;
    float T = m - 8.0f;

    for (int att = 0; att < 3; ++att) {
        const float scale = 256.0f / width;

        *(uint4*)&bins[4 * l] = make_uint4(0u, 0u, 0u, 0u);
        __builtin_amdgcn_wave_barrier();

#pragma unroll
        for (int i = 0; i < 32; ++i) {
            float vi = v[i];
            bool in = (vi >= lo);
            if (havePrev) {
                int pb = (int)fminf((vi - pLo) * pScale, 255.0f);
                in = (vi >= pLo) && (pb == pBkt);
            }
            if (in) {
                int bi = (int)fminf((vi - lo) * scale, 255.0f);
                bi = bi < 0 ? 0 : bi;
                atomicAdd(&bins[bi], 1u);
            }
        }
        __builtin_amdgcn_wave_barrier();

        uint4 c4 = *(const uint4*)&bins[4 * l];
        u32 tl  = c4.x + c4.y + c4.z + c4.w;
        u32 suf = tl;
#pragma unroll
        for (int d2 = 1; d2 < 64; d2 <<= 1) {
            u32 o = __shfl_down(suf, d2, 64);
            suf += (l + d2 < 64) ? o : 0u;
        }
        u32 above = suf - tl;
        u32 cs3 = base + above + c4.w;
        u32 cs2 = cs3 + c4.z;
        u32 cs1 = cs2 + c4.y;
        u32 cs0 = cs1 + c4.x;

        bool has = (cs3 <= 64);
        int eloc; u32 nloc;
        if      (cs0 <= 64) { eloc = 4 * l;     nloc = cs0; }
        else if (cs1 <= 64) { eloc = 4 * l + 1; nloc = cs1; }
        else if (cs2 <= 64) { eloc = 4 * l + 2; nloc = cs2; }
        else                { eloc = 4 * l + 3; nloc = cs3; }

        u64 bal = __ballot(has);
        const float bw = width * (1.0f / 256.0f);
        if (bal == 0ull) {
            havePrev = 1; pLo = lo; pScale = scale; pBkt = 255;
            lo = lo + 255.0f * bw; width = bw;
            T = lo;
            continue;
        }
        int src  = (int)__ffsll(bal) - 1;
        int eS   = __shfl(eloc, src, 64);
        u32 nAt  = (u32)__shfl((int)nloc, src, 64);
        T = lo + (float)eS * bw;
        if (nAt >= CPAD || eS == 0 || att == 2) break;
        havePrev = 1; pLo = lo; pScale = scale; pBkt = eS - 1;
        base = nAt;
        lo = lo + (float)(eS - 1) * bw; width = bw;
    }

    // ---- cursor compaction of candidates {v >= T} (cap 64) ----
    if (l == 0) cntAll[w] = 0u;
    __builtin_amdgcn_wave_barrier();
#pragma unroll
    for (int i = 0; i < 32; ++i) {
        if (v[i] >= T) {
            u32 slot = atomicAdd(&cntAll[w], 1u);
            if (slot < 64) {
                int col = ((i >> 3) << 9) + (l << 3) + (i & 7);
                selc[slot] = (u32)col;
            }
        }
    }
    __builtin_amdgcn_wave_barrier();
    int C = (int)cntAll[w]; C = C > 64 ? 64 : C;

    // ---- EXACT rescore (identical order to R5/R6: stride-4 accumulators) ----
    float sx = -3.0e38f;
    u32 mycol = 0;
    if (l < C) {
        mycol = selc[l];
        const float* kr = Kp + ((size_t)b * NKNOW + mycol) * 1024 + h * 64;
        float p0 = 0.f, p1 = 0.f, p2 = 0.f, p3 = 0.f;
#pragma unroll
        for (int d = 0; d < 64; d += 4) {
            float4 kv = *(const float4*)(kr + d);
            float4 qv = *(const float4*)&qrow[d];
            p0 = fmaf(qv.x, kv.x, p0);
            p1 = fmaf(qv.y, kv.y, p1);
            p2 = fmaf(qv.z, kv.z, p2);
            p3 = fmaf(qv.w, kv.w, p3);
        }
        sx = ((p0 + p1) + (p2 + p3)) * 0.125f;
    }

    // ---- exact all-pairs rank over C candidates (pk64: jax tie semantics) ----
    keys[l] = (l < C) ? pk64(sx, (int)mycol) : 0ull;
    __builtin_amdgcn_wave_barrier();
    u64 myk = keys[l];
    int rank = 0;
#pragma unroll 8
    for (int j = 0; j < C; ++j) rank += (keys[j] > myk) ? 1 : 0;
    const bool win = (l < C) && (rank < TOPK);

    // ---- softmax over exact top-32 ----
    float mx = win ? sx : -3.0e38f;
#pragma unroll
    for (int d2 = 1; d2 < 64; d2 <<= 1) mx = fmaxf(mx, __shfl_xor(mx, d2, 64));
    float e = win ? __expf(sx - mx) : 0.0f;
    float Z = e;
#pragma unroll
    for (int d2 = 1; d2 < 64; d2 <<= 1) Z += __shfl_xor(Z, d2, 64);
    const float invZ = 1.0f / Z;

    u64 bw2 = __ballot(win);
    if (win) {
        u32 slot = (u32)__popcll(bw2 & ((1ull << l) - 1ull));
        sel[slot] = (((u64)__float_as_uint(e)) << 32) | mycol;
    }
    __builtin_amdgcn_wave_barrier();

    // ---- V gather: unrolled x4 for memory-level parallelism ----
    const float* vbase = Vp + (size_t)b * NKNOW * 1024 + h * 64 + l;
    float acc = 0.0f;
#pragma unroll
    for (int j0 = 0; j0 < TOPK; j0 += 4) {
        u64 pc0 = sel[j0 + 0], pc1 = sel[j0 + 1], pc2 = sel[j0 + 2], pc3 = sel[j0 + 3];
        float v0 = vbase[(size_t)(u32)(pc0 & 0xFFFFFFFFu) * 1024];
        float v1 = vbase[(size_t)(u32)(pc1 & 0xFFFFFFFFu) * 1024];
        float v2 = vbase[(size_t)(u32)(pc2 & 0xFFFFFFFFu) * 1024];
        float v3 = vbase[(size_t)(u32)(pc3 & 0xFFFFFFFFu) * 1024];
        acc = fmaf(__uint_as_float((u32)(pc0 >> 32)) * invZ, v0, acc);
        acc = fmaf(__uint_as_float((u32)(pc1 >> 32)) * invZ, v1, acc);
        acc = fmaf(__uint_as_float((u32)(pc2 >> 32)) * invZ, v2, acc);
        acc = fmaf(__uint_as_float((u32)(pc3 >> 32)) * invZ, v3, acc);
    }
    size_t oidx = ((size_t)b * SEQ + s) * 1024 + h * 64 + l;
    ush hh = f2bf(acc);
    ctxh[oidx] = hh;
    ctxl[oidx] = f2bf(acc - bf2f(hh));
}

// ---------------------------------------------------------------------------
extern "C" void kernel_launch(void* const* d_in, const int* in_sizes, int n_in,
                              void* d_out, int out_size, void* d_ws, size_t ws_size,
                              hipStream_t stream)
{
    const float* x  = (const float*)d_in[0];
    const float* ke = (const float*)d_in[1];
    const float* Wq = (const float*)d_in[2];
    const float* bq = (const float*)d_in[3];
    const float* Wk = (const float*)d_in[4];
    const float* bk = (const float*)d_in[5];
    const float* Wv = (const float*)d_in[6];
    const float* bv = (const float*)d_in[7];
    const float* Wo = (const float*)d_in[8];
    const float* bo = (const float*)d_in[9];
    float* out = (float*)d_out;

    const size_t NB = (size_t)4096 * 1024;
    const size_t NW = (size_t)1024 * 1024;

    char* p = (char*)d_ws;
    float *Qp = (float*)p;  p += NB * 4;
    float *Kp = (float*)p;  p += NB * 4;
    float *Vp = (float*)p;  p += NB * 4;
    ush *Qb  = (ush*)p;     p += NB * 2;
    ush *Kb  = (ush*)p;     p += NB * 2;
    ush *keb = (ush*)p;     p += NB * 2;
    ush *Wvb = (ush*)p;     p += NW * 2;
    ush *Woh = (ush*)p;     p += NW * 2;
    ush *Wol = (ush*)p;     p += NW * 2;
    ush *ctxh = (ush*)p;    p += NB * 2;
    ush *ctxl = (ush*)p;    p += NB * 2;
    ush *Sc = (ush*)p;
    const size_t fixedBytes = (size_t)(p - (char*)d_ws);

    int bhg = 1;
    {
        const int tiers[6] = {32, 16, 8, 4, 2, 1};
        for (int i = 0; i < 6; ++i) {
            size_t scB = (size_t)tiers[i] * SEQ * NKNOW * 2;   // bf16 spill
            if (fixedBytes + scB <= ws_size) { bhg = tiers[i]; break; }
        }
    }

    dim3 blk(256);

    // converts / splits
    hipLaunchKernelGGL(conv_bf16,  dim3((int)(NB / 1024)), blk, 0, stream, ke, keb, (int)NB);
    hipLaunchKernelGGL(conv_bf16,  dim3((int)(NW / 1024)), blk, 0, stream, Wv, Wvb, (int)NW);
    hipLaunchKernelGGL(split_bf16, dim3((int)(NW / 1024)), blk, 0, stream, Wo, Woh, Wol, (int)NW);

    // Q+K projections merged (1024 blocks, 4/CU): bitwise-identical to R6
    hipLaunchKernelGGL(gemm_f32_qk, dim3(64, 8, 2), blk, 0, stream,
                       x,  Wq, bq, Qp, Qb,
                       ke, Wk, bk, Kp, Kb);

    // V projection: 1-term bf16 MFMA (magnitude-only)
    hipLaunchKernelGGL(gemm_mfma_1t, dim3(64, 8), blk, 0, stream, keb, Wvb, bv, Vp);

    for (int bh0 = 0; bh0 < 32; bh0 += bhg) {
        hipLaunchKernelGGL(scores_bf16, dim3(SEQ / 128, NKNOW / 128, bhg), blk, 0, stream,
                           Qb, Kb, Sc, bh0);
        hipLaunchKernelGGL(topk_rescore2, dim3(bhg * SEQ / 4), blk, 0, stream,
                           Sc, Qp, Kp, Vp, ctxh, ctxl, bh0);
    }

    // O projection: 3-term MFMA -> fp32 out
    hipLaunchKernelGGL(gemm_mfma_split, dim3(64, 8), blk, 0, stream,
                       ctxh, ctxl, Woh, Wol, bo, out);
}